// Round 3
// baseline (558.655 us; speedup 1.0000x reference)
//
#include <hip/hip_runtime.h>
#include <hip/hip_bf16.h>

// ---------------------------------------------------------------------------
// GCN link predictor, R11: feature-sliced gathers (L2-capacity fix, round 2).
// R10 post-mortem: split-z decode worked (decode off top-5); new #1 is
// k_gather1 65us / FETCH 166MB -- same capacity pathology (xw1 12.8MB vs
// 4MB/XCD L2, ~69% miss floor). Fix: store xw1 as 4 slices [N][16] (3.2MB,
// L2-fits) and run gather1 as 4 independent feature passes; xw2 as 2 slices,
// gather2 pass p writes zlo/zhi directly. gemm1/2 write sliced layout
// (nt == slice index). 16 slots x 4 lanes per wave, bfx4 loads.
//   h = relu(b1 + dv*(dv*xw1[v] + sum dinv[s]*xw1[s])),  xw1 = x @ W1 (MFMA)
//   z = b2 + dv*(dv*xw2[v] + sum dinv[s]*xw2[s]),        xw2 = h @ W2 (MFMA)
//   logits[e] = dot(z[src], z[dst]) over [pos; neg]
// Output: FLOAT32 [logits(2E)][edge row0(2E)][row1(2E)] (established R2).
// ---------------------------------------------------------------------------

#define IN_F  128
#define HID_F 64
#define OUT_F 32
#define NA    200      // edge-chunk blocks for hist/scatter
#define NBS   512      // histogram stride (>= NB=391 buckets of 256 nodes)

// workspace element offsets (4-byte units); N=100000, E=1600000; 58.8 MB
#define OFF_FLAGS   0          // 2 ints
#define OFF_W1T     64         // 8192 bf16 = 4096 ints
#define OFF_W2T     4160       // 2048 bf16 = 1024 ints
#define OFF_HIST    5200       // NA*NBS = 102400 ints
#define OFF_BTOT    107600     // 512 ints
#define OFF_ROWP    108200     // N+1 ints
#define OFF_DINV    208300     // N floats
#define OFF_EPAIRS  308300     // 2E ints (int2 pairs; byte-offset % 8 == 0)
#define OFF_CSR     3508300    // E ints
#define OFF_XW1     5108300    // 4 slices of N*16 bf16 (3.2M ints total)
#define OFF_H       8308300    // N*64 bf16
#define OFF_XW2     11508300   // 2 slices of N*16 bf16 (1.6M ints total)
#define OFF_ZLO     13108300   // N*16 bf16 = 800k ints (3.2MB, fits XCD L2)
#define OFF_ZHI     13908300   // N*16 bf16 -> end 14708300

typedef short short8 __attribute__((ext_vector_type(8)));
typedef float f32x4  __attribute__((ext_vector_type(4)));
typedef unsigned short bfx8 __attribute__((ext_vector_type(8)));
typedef unsigned short bfx4 __attribute__((ext_vector_type(4)));

__device__ __forceinline__ float ldf(const void* p, int i, int f32) {
  if (f32) return ((const float*)p)[i];
  unsigned int w = ((unsigned int)((const unsigned short*)p)[i]) << 16;
  return __uint_as_float(w);
}
__device__ __forceinline__ int ldi(const void* p, long long i, int i64) {
  if (i64) return (int)((const long long*)p)[i];
  return ((const int*)p)[i];
}
// non-temporal index load: single-use streams, keep out of L2
__device__ __forceinline__ int ldi_nt(const void* p, long long i, int i64) {
  if (i64) return (int)__builtin_nontemporal_load(((const long long*)p) + i);
  return __builtin_nontemporal_load(((const int*)p) + i);
}
__device__ __forceinline__ int clampN(int v, int N) {
  unsigned u = (unsigned)v;
  return (u < (unsigned)N) ? v : 0;
}
__device__ __forceinline__ unsigned short f2bf(float f) {   // RNE f32->bf16
  unsigned u = __float_as_uint(f);
  return (unsigned short)((u + 0x7FFFu + ((u >> 16) & 1u)) >> 16);
}
__device__ __forceinline__ float bf2f(unsigned short h) {
  return __uint_as_float(((unsigned)h) << 16);
}

// --- prep (grid 1): detect dtypes + transpose weights ----------------------
__global__ __launch_bounds__(256) void k_prep(const void* __restrict__ x,
                                              const void* __restrict__ pe,
                                              const void* __restrict__ W1,
                                              const void* __restrict__ W2,
                                              int* __restrict__ flags,
                                              unsigned short* __restrict__ w1t,
                                              unsigned short* __restrict__ w2t) {
  __shared__ int s_big, s_nzodd;
  int t = threadIdx.x;
  if (t == 0) { s_big = 0; s_nzodd = 0; }
  __syncthreads();
  int nbig = 0, nz = 0;
  const unsigned short* xb = (const unsigned short*)x;
  for (int i = t; i < 4096; i += 256) {
    int ex = (xb[i] >> 7) & 0xFF;
    if (ex >= 147) nbig++;               // |v|>=2^20 impossible for N(0,1) bf16
  }
  const int* pi = (const int*)pe;
  for (int i = t; i < 2048; i += 256) {
    if (pi[2 * i + 1] != 0) nz++;        // int64 hi-words all zero
  }
  atomicAdd(&s_big, nbig);
  atomicAdd(&s_nzodd, nz);
  __syncthreads();
  int f32 = (s_big > 400) ? 1 : 0;
  if (t == 0) {
    flags[0] = f32;
    flags[1] = (s_nzodd < 100) ? 1 : 0;
  }
  for (int i = t; i < HID_F * IN_F; i += 256) {   // W1T[n*128+k] = W1[k*64+n]
    int n = i >> 7, k = i & 127;
    w1t[i] = f2bf(ldf(W1, k * HID_F + n, f32));
  }
  for (int i = t; i < OUT_F * HID_F; i += 256) {  // W2T[n*64+k] = W2[k*32+n]
    int n = i >> 6, k = i & 63;
    w2t[i] = f2bf(ldf(W2, k * OUT_F + n, f32));
  }
}

// --- CSR build pass 1: per-chunk LDS histogram over buckets ---------------
__global__ __launch_bounds__(256) void k_hist(const void* __restrict__ pe,
                                              int* __restrict__ histmat,
                                              const int* __restrict__ flags,
                                              int E, int N, int CH) {
  __shared__ int hist[NBS];
  int t = threadIdx.x;
  for (int i = t; i < NBS; i += 256) hist[i] = 0;
  __syncthreads();
  int i64 = flags[1];
  int base = blockIdx.x * CH, end = min(base + CH, E);
  for (int e = base + t; e < end; e += 256) {
    int dst = clampN(ldi_nt(pe, (long long)E + e, i64), N);
    atomicAdd(&hist[dst >> 8], 1);       // LDS atomic
  }
  __syncthreads();
  for (int i = t; i < NBS; i += 256) histmat[blockIdx.x * NBS + i] = hist[i];
}

// --- pass 2: per-bucket column exclusive scan + bucket totals --------------
__global__ __launch_bounds__(256) void k_colscan(int* __restrict__ histmat,
                                                 int* __restrict__ btot) {
  __shared__ int a[256];
  int b = blockIdx.x, t = threadIdx.x;
  int h = (t < NA) ? histmat[t * NBS + b] : 0;
  a[t] = h;
  __syncthreads();
  for (int off = 1; off < 256; off <<= 1) {
    int v = (t >= off) ? a[t - off] : 0;
    __syncthreads();
    a[t] += v;
    __syncthreads();
  }
  if (t < NA) histmat[t * NBS + b] = a[t] - h;   // exclusive within column
  if (t == 255) btot[b] = a[255];
}

// --- pass 3: scatter pairs into bucket-sorted order (LDS cursors only) -----
__global__ __launch_bounds__(256) void k_scatter(const void* __restrict__ pe,
                                                 const int* __restrict__ histmat,
                                                 const int* __restrict__ btot,
                                                 int2* __restrict__ epairs,
                                                 const int* __restrict__ flags,
                                                 int E, int N, int NB, int CH) {
  __shared__ int sc[NBS];
  __shared__ int cur[NBS];
  int t = threadIdx.x;
  int o0 = (t < NB) ? btot[t] : 0;
  int o1 = (t + 256 < NB) ? btot[t + 256] : 0;
  sc[t] = o0; sc[t + 256] = o1;
  __syncthreads();
  for (int off = 1; off < NBS; off <<= 1) {      // Hillis-Steele, 2 slots/thread
    int v0 = (t >= off) ? sc[t - off] : 0;
    int v1 = (t + 256 >= off) ? sc[t + 256 - off] : 0;
    __syncthreads();
    sc[t] += v0; sc[t + 256] += v1;
    __syncthreads();
  }
  const int* row = histmat + blockIdx.x * NBS;   // contiguous row
  cur[t]       = sc[t] - o0 + row[t];            // bucket base + block cursor
  cur[t + 256] = sc[t + 256] - o1 + row[t + 256];
  __syncthreads();
  int i64 = flags[1];
  int base = blockIdx.x * CH, end = min(base + CH, E);
  for (int e = base + t; e < end; e += 256) {
    int src = clampN(ldi_nt(pe, e, i64), N);
    int dst = clampN(ldi_nt(pe, (long long)E + e, i64), N);
    int pos = atomicAdd(&cur[dst >> 8], 1);      // LDS atomic
    epairs[pos] = make_int2(src, dst);
  }
}

// --- pass 4: per-bucket counting sort -> csr; emits rowp + dinv ------------
__global__ __launch_bounds__(256) void k_bsort(const int2* __restrict__ epairs,
                                               const int* __restrict__ btot,
                                               int* __restrict__ rowp,
                                               float* __restrict__ dinv,
                                               int* __restrict__ csr,
                                               int N, int NB) {
  __shared__ int red[256];
  __shared__ int cnt[256];
  __shared__ int cur2[256];
  __shared__ int s_start;
  int b = blockIdx.x, t = threadIdx.x;
  int acc = 0;
  for (int i = t; i < b; i += 256) acc += btot[i];   // bstart = sum btot[<b]
  red[t] = acc;
  __syncthreads();
  for (int off = 128; off > 0; off >>= 1) {
    if (t < off) red[t] += red[t + off];
    __syncthreads();
  }
  if (t == 0) s_start = red[0];
  __syncthreads();
  int bstart = s_start, bend = bstart + btot[b];
  int node0 = b << 8, nn = min(N - node0, 256);
  cnt[t] = 0;
  __syncthreads();
  for (int j = bstart + t; j < bend; j += 256)
    atomicAdd(&cnt[epairs[j].y - node0], 1);         // LDS atomic
  __syncthreads();
  int c = cnt[t];
  red[t] = c;
  __syncthreads();
  for (int off = 1; off < 256; off <<= 1) {          // inclusive scan
    int v = (t >= off) ? red[t - off] : 0;
    __syncthreads();
    red[t] += v;
    __syncthreads();
  }
  int excl = red[t] - c;
  if (t < nn) {
    rowp[node0 + t] = bstart + excl;
    dinv[node0 + t] = 1.0f / sqrtf((float)(c + 1));  // +1 self loop
    cur2[t] = bstart + excl;
  }
  __syncthreads();
  for (int j = bstart + t; j < bend; j += 256) {
    int2 p = epairs[j];
    int pos = atomicAdd(&cur2[p.y - node0], 1);      // LDS atomic
    csr[pos] = p.x;                                  // ~16KB window: L2-local
  }
  if (b == NB - 1 && t == 0) rowp[N] = bend;
}

// --- gemm1 (MFMA): xw1 = x @ W1, sliced bf16 out ---------------------------
// Slice layout: xw1[nt][N][16] -- nt IS the 16-feature slice index.
__global__ __launch_bounds__(256) void k_gemm1(const void* __restrict__ x,
                                               const unsigned short* __restrict__ w1t,
                                               unsigned short* __restrict__ xw1,
                                               const int* __restrict__ flags, int N) {
  int w = threadIdx.x >> 6, lane = threadIdx.x & 63;
  int m = lane & 15, quad = lane >> 4;
  int r0 = blockIdx.x * 64 + w * 16;
  int rr = r0 + m; if (rr >= N) rr = N - 1;
  int f32 = flags[0];
  short8 A[4];
  if (f32) {
    const float* xf = (const float*)x + (size_t)rr * IN_F;
#pragma unroll
    for (int ks = 0; ks < 4; ++ks) {
      const float* p = xf + ks * 32 + quad * 8;
      f32x4 u0 = __builtin_nontemporal_load((const f32x4*)p);
      f32x4 u1 = __builtin_nontemporal_load((const f32x4*)(p + 4));
      short8 a;
#pragma unroll
      for (int j = 0; j < 4; ++j) { a[j] = (short)f2bf(u0[j]); a[4 + j] = (short)f2bf(u1[j]); }
      A[ks] = a;
    }
  } else {
    const unsigned short* xb = (const unsigned short*)x + (size_t)rr * IN_F;
#pragma unroll
    for (int ks = 0; ks < 4; ++ks)
      A[ks] = __builtin_nontemporal_load((const short8*)(xb + ks * 32 + quad * 8));
  }
#pragma unroll
  for (int nt = 0; nt < 4; ++nt) {
    f32x4 acc = {0.f, 0.f, 0.f, 0.f};
#pragma unroll
    for (int ks = 0; ks < 4; ++ks) {
      short8 Bf = *(const short8*)(w1t + (nt * 16 + m) * IN_F + ks * 32 + quad * 8);
      acc = __builtin_amdgcn_mfma_f32_16x16x32_bf16(A[ks], Bf, acc, 0, 0, 0);
    }
#pragma unroll
    for (int reg = 0; reg < 4; ++reg) {
      int row = r0 + quad * 4 + reg;
      if (row < N)
        xw1[(size_t)nt * N * 16 + (size_t)row * 16 + m] = f2bf(acc[reg]);
    }
  }
}

// --- gather1 pass p: h[:, p*16:(p+1)*16] from slice xw1p (3.2MB, L2-fits) --
// 16 neighbor slots x 4 lanes; each lane handles 4 features (bfx4 = 8B).
__global__ __launch_bounds__(256) void k_gather1(const int* __restrict__ row_ptr,
                                                 const int* __restrict__ csr_src,
                                                 const float* __restrict__ dinv,
                                                 const unsigned short* __restrict__ xw1p,
                                                 const void* __restrict__ b1,
                                                 unsigned short* __restrict__ h,
                                                 const int* __restrict__ flags,
                                                 int N, int p) {
  int v = blockIdx.x * 4 + (threadIdx.x >> 6);
  if (v >= N) return;
  int lane = threadIdx.x & 63;
  int slot = lane >> 2, l4 = lane & 3;
  int start = row_ptr[v], end = row_ptr[v + 1];
  float a[4] = {0.f, 0.f, 0.f, 0.f};
  for (int j = start + slot; j < end; j += 16) {
    int s = __builtin_nontemporal_load(csr_src + j);   // sequential stream
    float ds = dinv[s];
    bfx4 wv = *(const bfx4*)(xw1p + (size_t)s * 16 + l4 * 4);
#pragma unroll
    for (int q = 0; q < 4; ++q) a[q] += ds * bf2f(wv[q]);
  }
#pragma unroll
  for (int q = 0; q < 4; ++q) {
    a[q] += __shfl_xor(a[q], 4);
    a[q] += __shfl_xor(a[q], 8);
    a[q] += __shfl_xor(a[q], 16);
    a[q] += __shfl_xor(a[q], 32);
  }
  if (slot == 0) {
    float dv = dinv[v];
    bfx4 sw = *(const bfx4*)(xw1p + (size_t)v * 16 + l4 * 4);
    int f32 = flags[0];
    bfx4 r;
#pragma unroll
    for (int q = 0; q < 4; ++q) {
      float val = ldf(b1, p * 16 + l4 * 4 + q, f32) + dv * (dv * bf2f(sw[q]) + a[q]);
      r[q] = f2bf(fmaxf(val, 0.f));
    }
    *(bfx4*)(h + (size_t)v * HID_F + p * 16 + l4 * 4) = r;
  }
}

// --- gemm2 (MFMA): xw2 = h @ W2, sliced bf16 out (2 slices [N][16]) --------
__global__ __launch_bounds__(256) void k_gemm2(const unsigned short* __restrict__ h,
                                               const unsigned short* __restrict__ w2t,
                                               unsigned short* __restrict__ xw2, int N) {
  int w = threadIdx.x >> 6, lane = threadIdx.x & 63;
  int m = lane & 15, quad = lane >> 4;
  int r0 = blockIdx.x * 64 + w * 16;
  int rr = r0 + m; if (rr >= N) rr = N - 1;
  const unsigned short* hb = h + (size_t)rr * HID_F;
  short8 A[2];
#pragma unroll
  for (int ks = 0; ks < 2; ++ks)
    A[ks] = *(const short8*)(hb + ks * 32 + quad * 8);
#pragma unroll
  for (int nt = 0; nt < 2; ++nt) {
    f32x4 acc = {0.f, 0.f, 0.f, 0.f};
#pragma unroll
    for (int ks = 0; ks < 2; ++ks) {
      short8 Bf = *(const short8*)(w2t + (nt * 16 + m) * HID_F + ks * 32 + quad * 8);
      acc = __builtin_amdgcn_mfma_f32_16x16x32_bf16(A[ks], Bf, acc, 0, 0, 0);
    }
#pragma unroll
    for (int reg = 0; reg < 4; ++reg) {
      int row = r0 + quad * 4 + reg;
      if (row < N)
        xw2[(size_t)nt * N * 16 + (size_t)row * 16 + m] = f2bf(acc[reg]);
    }
  }
}

// --- gather2 pass p: z slice from xw2p (3.2MB, L2-fits) -> zlo/zhi ---------
__global__ __launch_bounds__(256) void k_gather2(const int* __restrict__ row_ptr,
                                                 const int* __restrict__ csr_src,
                                                 const float* __restrict__ dinv,
                                                 const unsigned short* __restrict__ xw2p,
                                                 const void* __restrict__ b2,
                                                 unsigned short* __restrict__ zout,
                                                 const int* __restrict__ flags,
                                                 int N, int p) {
  int v = blockIdx.x * 4 + (threadIdx.x >> 6);
  if (v >= N) return;
  int lane = threadIdx.x & 63;
  int slot = lane >> 2, l4 = lane & 3;
  int start = row_ptr[v], end = row_ptr[v + 1];
  float a[4] = {0.f, 0.f, 0.f, 0.f};
  for (int j = start + slot; j < end; j += 16) {
    int s = __builtin_nontemporal_load(csr_src + j);   // sequential stream
    float ds = dinv[s];
    bfx4 wv = *(const bfx4*)(xw2p + (size_t)s * 16 + l4 * 4);
#pragma unroll
    for (int q = 0; q < 4; ++q) a[q] += ds * bf2f(wv[q]);
  }
#pragma unroll
  for (int q = 0; q < 4; ++q) {
    a[q] += __shfl_xor(a[q], 4);
    a[q] += __shfl_xor(a[q], 8);
    a[q] += __shfl_xor(a[q], 16);
    a[q] += __shfl_xor(a[q], 32);
  }
  if (slot == 0) {
    float dv = dinv[v];
    bfx4 sw = *(const bfx4*)(xw2p + (size_t)v * 16 + l4 * 4);
    int f32 = flags[0];
    bfx4 r;
#pragma unroll
    for (int q = 0; q < 4; ++q)
      r[q] = f2bf(ldf(b2, p * 16 + l4 * 4 + q, f32) + dv * (dv * bf2f(sw[q]) + a[q]));
    *(bfx4*)(zout + (size_t)v * 16 + l4 * 4) = r;
  }
}

// --- decode, two passes over half-tables (3.2MB each, XCD-L2-resident) -----
__global__ __launch_bounds__(256) void k_decode2(const void* __restrict__ pe,
                                                 const void* __restrict__ ne,
                                                 const unsigned short* __restrict__ zt,
                                                 float* __restrict__ out,
                                                 const int* __restrict__ flags,
                                                 int E, int N, int finalp) {
  int tid = blockIdx.x * 256 + threadIdx.x;
  int e = tid >> 1, g = tid & 1;
  int twoE = 2 * E;
  if (e >= twoE) return;
  int i64 = flags[1];
  int idx;
  if (e < E) idx = ldi_nt(pe, g ? (long long)E + e : (long long)e, i64);
  else       idx = ldi_nt(ne, g ? (long long)e : (long long)(e - E), i64);
  int other = __shfl_xor(idx, 1);
  int src = g ? other : idx;
  int dst = g ? idx : other;
  if (!finalp) {
    if (g == 0) __builtin_nontemporal_store((float)src, out + twoE + e);
    else        __builtin_nontemporal_store((float)dst, out + 2 * twoE + e);
  }
  int cs = clampN(src, N), cd = clampN(dst, N);
  bfx8 a = *(const bfx8*)(zt + (size_t)cs * 16 + g * 8);
  bfx8 b = *(const bfx8*)(zt + (size_t)cd * 16 + g * 8);
  float s = 0.f;
#pragma unroll
  for (int q = 0; q < 8; ++q) s += bf2f(a[q]) * bf2f(b[q]);
  s += __shfl_xor(s, 1);
  if (g == 0) {
    if (!finalp) {
      out[e] = s;                               // partial; L3 holds for pass2
    } else {
      float t = out[e] + s;
      t = fminf(fmaxf(t, -500.0f), 500.0f);     // insurance rail (R2 notes)
      __builtin_nontemporal_store(t, out + e);
    }
  }
}

extern "C" void kernel_launch(void* const* d_in, const int* in_sizes, int n_in,
                              void* d_out, int out_size, void* d_ws, size_t ws_size,
                              hipStream_t stream) {
  const void* x  = d_in[0];
  const void* W1 = d_in[1];
  const void* b1 = d_in[2];
  const void* W2 = d_in[3];
  const void* b2 = d_in[4];
  const void* pe = d_in[5];
  const void* ne = d_in[6];
  int N = in_sizes[0] / IN_F;       // 100000
  int E = in_sizes[5] / 2;          // 1600000
  int NB = (N + 255) >> 8;          // 391 buckets
  int CH = (E + NA - 1) / NA;       // 8000 edges/chunk

  int*   ip    = (int*)d_ws;
  float* ws    = (float*)d_ws;
  int*   flags = ip + OFF_FLAGS;
  unsigned short* w1t = (unsigned short*)(ip + OFF_W1T);
  unsigned short* w2t = (unsigned short*)(ip + OFF_W2T);
  int*   hist  = ip + OFF_HIST;
  int*   btot  = ip + OFF_BTOT;
  int*   rowp  = ip + OFF_ROWP;
  float* dinv  = ws + OFF_DINV;
  int2*  epairs= (int2*)(ip + OFF_EPAIRS);
  int*   csr   = ip + OFF_CSR;
  unsigned short* xw1 = (unsigned short*)(ip + OFF_XW1);
  unsigned short* h   = (unsigned short*)(ip + OFF_H);
  unsigned short* xw2 = (unsigned short*)(ip + OFF_XW2);
  unsigned short* zlo = (unsigned short*)(ip + OFF_ZLO);
  unsigned short* zhi = (unsigned short*)(ip + OFF_ZHI);
  float* out   = (float*)d_out;

  k_prep<<<1, 256, 0, stream>>>(x, pe, W1, W2, flags, w1t, w2t);
  k_hist<<<NA, 256, 0, stream>>>(pe, hist, flags, E, N, CH);
  k_colscan<<<NB, 256, 0, stream>>>(hist, btot);
  k_scatter<<<NA, 256, 0, stream>>>(pe, hist, btot, epairs, flags, E, N, NB, CH);
  k_bsort<<<NB, 256, 0, stream>>>(epairs, btot, rowp, dinv, csr, N, NB);
  k_gemm1<<<(N + 63) / 64, 256, 0, stream>>>(x, w1t, xw1, flags, N);
  for (int p = 0; p < 4; ++p)
    k_gather1<<<(N + 3) / 4, 256, 0, stream>>>(rowp, csr, dinv,
        xw1 + (size_t)p * N * 16, b1, h, flags, N, p);
  k_gemm2<<<(N + 63) / 64, 256, 0, stream>>>(h, w2t, xw2, N);
  for (int p = 0; p < 2; ++p)
    k_gather2<<<(N + 3) / 4, 256, 0, stream>>>(rowp, csr, dinv,
        xw2 + (size_t)p * N * 16, b2, p ? zhi : zlo, flags, N, p);
  int DB = (4 * E + 255) / 256;     // 2 lanes/edge over 2E edges
  k_decode2<<<DB, 256, 0, stream>>>(pe, ne, zlo, out, flags, E, N, 0);
  k_decode2<<<DB, 256, 0, stream>>>(pe, ne, zhi, out, flags, E, N, 1);
}

// Round 4
// 387.346 us; speedup vs baseline: 1.4423x; 1.4423x over previous
//
#include <hip/hip_runtime.h>
#include <hip/hip_bf16.h>

// ---------------------------------------------------------------------------
// GCN link predictor, R12: revert to R8 single-pass structure + 64B-aligned
// tables. R11 lesson (counter-verified): gathers/decode are vector-memory
// REQUEST-throughput bound (~1.1 req/cyc/CU), not HBM/L2-capacity bound --
// L2-resident split tables cut FETCH 10x but duration went UP with request
// count. So: minimize requests (single pass, 16B loads) and minimize LINES
// PER REQUEST. Old offsets put xw1/h/xw2/z at byte%64==48: every 128B row
// spanned 3 lines (not 2), every 64B z row spanned 2 (not 1). New offset map
// aligns all table bases to 128B. Algorithm identical to R8/R9.
//   h = relu(b1 + dv*(dv*xw1[v] + sum dinv[s]*xw1[s])),  xw1 = x @ W1 (MFMA)
//   z = b2 + dv*(dv*xw2[v] + sum dinv[s]*xw2[s]),        xw2 = h @ W2 (MFMA)
//   logits[e] = dot(z[src], z[dst]) over [pos; neg]
// Output: FLOAT32 [logits(2E)][edge row0(2E)][row1(2E)] (established R2).
// ---------------------------------------------------------------------------

#define IN_F  128
#define HID_F 64
#define OUT_F 32
#define NA    200      // edge-chunk blocks for hist/scatter
#define NBS   512      // histogram stride (>= NB=391 buckets of 256 nodes)

// workspace element offsets (4-byte units); all table bases 128B-aligned.
// N=100000, E=1600000; end = 14,708,096 ints = 58.83 MB.
#define OFF_FLAGS   0          // 2 ints
#define OFF_W1T     32         // 8192 bf16 = 4096 ints
#define OFF_W2T     4128       // 2048 bf16 = 1024 ints
#define OFF_HIST    5152       // NA*NBS = 102400 ints
#define OFF_BTOT    107552     // 512 ints
#define OFF_ROWP    108064     // N+1 ints (-> 208065)
#define OFF_DINV    208096     // N floats
#define OFF_EPAIRS  308096     // 2E ints (int2 pairs; byte%8==0)
#define OFF_CSR     3508096    // E ints
#define OFF_XW1     5108096    // N*64 bf16 = 3.2M ints (base byte%128==0)
#define OFF_H       8308096    // N*64 bf16
#define OFF_XW2     11508096   // N*32 bf16 = 1.6M ints
#define OFF_Z       13108096   // N*32 bf16 -> end 14708096

typedef short short8 __attribute__((ext_vector_type(8)));
typedef float f32x4  __attribute__((ext_vector_type(4)));
typedef unsigned short bfx8 __attribute__((ext_vector_type(8)));
typedef unsigned short bfx4 __attribute__((ext_vector_type(4)));

__device__ __forceinline__ float ldf(const void* p, int i, int f32) {
  if (f32) return ((const float*)p)[i];
  unsigned int w = ((unsigned int)((const unsigned short*)p)[i]) << 16;
  return __uint_as_float(w);
}
__device__ __forceinline__ int ldi(const void* p, long long i, int i64) {
  if (i64) return (int)((const long long*)p)[i];
  return ((const int*)p)[i];
}
// non-temporal index load: single-use streams, keep out of L2
__device__ __forceinline__ int ldi_nt(const void* p, long long i, int i64) {
  if (i64) return (int)__builtin_nontemporal_load(((const long long*)p) + i);
  return __builtin_nontemporal_load(((const int*)p) + i);
}
__device__ __forceinline__ int clampN(int v, int N) {
  unsigned u = (unsigned)v;
  return (u < (unsigned)N) ? v : 0;
}
__device__ __forceinline__ unsigned short f2bf(float f) {   // RNE f32->bf16
  unsigned u = __float_as_uint(f);
  return (unsigned short)((u + 0x7FFFu + ((u >> 16) & 1u)) >> 16);
}
__device__ __forceinline__ float bf2f(unsigned short h) {
  return __uint_as_float(((unsigned)h) << 16);
}

// --- prep (grid 1): detect dtypes + transpose weights ----------------------
__global__ __launch_bounds__(256) void k_prep(const void* __restrict__ x,
                                              const void* __restrict__ pe,
                                              const void* __restrict__ W1,
                                              const void* __restrict__ W2,
                                              int* __restrict__ flags,
                                              unsigned short* __restrict__ w1t,
                                              unsigned short* __restrict__ w2t) {
  __shared__ int s_big, s_nzodd;
  int t = threadIdx.x;
  if (t == 0) { s_big = 0; s_nzodd = 0; }
  __syncthreads();
  int nbig = 0, nz = 0;
  const unsigned short* xb = (const unsigned short*)x;
  for (int i = t; i < 4096; i += 256) {
    int ex = (xb[i] >> 7) & 0xFF;
    if (ex >= 147) nbig++;               // |v|>=2^20 impossible for N(0,1) bf16
  }
  const int* pi = (const int*)pe;
  for (int i = t; i < 2048; i += 256) {
    if (pi[2 * i + 1] != 0) nz++;        // int64 hi-words all zero
  }
  atomicAdd(&s_big, nbig);
  atomicAdd(&s_nzodd, nz);
  __syncthreads();
  int f32 = (s_big > 400) ? 1 : 0;
  if (t == 0) {
    flags[0] = f32;
    flags[1] = (s_nzodd < 100) ? 1 : 0;
  }
  for (int i = t; i < HID_F * IN_F; i += 256) {   // W1T[n*128+k] = W1[k*64+n]
    int n = i >> 7, k = i & 127;
    w1t[i] = f2bf(ldf(W1, k * HID_F + n, f32));
  }
  for (int i = t; i < OUT_F * HID_F; i += 256) {  // W2T[n*64+k] = W2[k*32+n]
    int n = i >> 6, k = i & 63;
    w2t[i] = f2bf(ldf(W2, k * OUT_F + n, f32));
  }
}

// --- CSR build pass 1: per-chunk LDS histogram over buckets ---------------
__global__ __launch_bounds__(256) void k_hist(const void* __restrict__ pe,
                                              int* __restrict__ histmat,
                                              const int* __restrict__ flags,
                                              int E, int N, int CH) {
  __shared__ int hist[NBS];
  int t = threadIdx.x;
  for (int i = t; i < NBS; i += 256) hist[i] = 0;
  __syncthreads();
  int i64 = flags[1];
  int base = blockIdx.x * CH, end = min(base + CH, E);
  for (int e = base + t; e < end; e += 256) {
    int dst = clampN(ldi_nt(pe, (long long)E + e, i64), N);
    atomicAdd(&hist[dst >> 8], 1);       // LDS atomic
  }
  __syncthreads();
  for (int i = t; i < NBS; i += 256) histmat[blockIdx.x * NBS + i] = hist[i];
}

// --- pass 2: per-bucket column exclusive scan + bucket totals --------------
__global__ __launch_bounds__(256) void k_colscan(int* __restrict__ histmat,
                                                 int* __restrict__ btot) {
  __shared__ int a[256];
  int b = blockIdx.x, t = threadIdx.x;
  int h = (t < NA) ? histmat[t * NBS + b] : 0;
  a[t] = h;
  __syncthreads();
  for (int off = 1; off < 256; off <<= 1) {
    int v = (t >= off) ? a[t - off] : 0;
    __syncthreads();
    a[t] += v;
    __syncthreads();
  }
  if (t < NA) histmat[t * NBS + b] = a[t] - h;   // exclusive within column
  if (t == 255) btot[b] = a[255];
}

// --- pass 3: scatter pairs into bucket-sorted order (LDS cursors only) -----
__global__ __launch_bounds__(256) void k_scatter(const void* __restrict__ pe,
                                                 const int* __restrict__ histmat,
                                                 const int* __restrict__ btot,
                                                 int2* __restrict__ epairs,
                                                 const int* __restrict__ flags,
                                                 int E, int N, int NB, int CH) {
  __shared__ int sc[NBS];
  __shared__ int cur[NBS];
  int t = threadIdx.x;
  int o0 = (t < NB) ? btot[t] : 0;
  int o1 = (t + 256 < NB) ? btot[t + 256] : 0;
  sc[t] = o0; sc[t + 256] = o1;
  __syncthreads();
  for (int off = 1; off < NBS; off <<= 1) {      // Hillis-Steele, 2 slots/thread
    int v0 = (t >= off) ? sc[t - off] : 0;
    int v1 = (t + 256 >= off) ? sc[t + 256 - off] : 0;
    __syncthreads();
    sc[t] += v0; sc[t + 256] += v1;
    __syncthreads();
  }
  const int* row = histmat + blockIdx.x * NBS;   // contiguous row
  cur[t]       = sc[t] - o0 + row[t];            // bucket base + block cursor
  cur[t + 256] = sc[t + 256] - o1 + row[t + 256];
  __syncthreads();
  int i64 = flags[1];
  int base = blockIdx.x * CH, end = min(base + CH, E);
  for (int e = base + t; e < end; e += 256) {
    int src = clampN(ldi_nt(pe, e, i64), N);
    int dst = clampN(ldi_nt(pe, (long long)E + e, i64), N);
    int pos = atomicAdd(&cur[dst >> 8], 1);      // LDS atomic
    epairs[pos] = make_int2(src, dst);
  }
}

// --- pass 4: per-bucket counting sort -> csr; emits rowp + dinv ------------
__global__ __launch_bounds__(256) void k_bsort(const int2* __restrict__ epairs,
                                               const int* __restrict__ btot,
                                               int* __restrict__ rowp,
                                               float* __restrict__ dinv,
                                               int* __restrict__ csr,
                                               int N, int NB) {
  __shared__ int red[256];
  __shared__ int cnt[256];
  __shared__ int cur2[256];
  __shared__ int s_start;
  int b = blockIdx.x, t = threadIdx.x;
  int acc = 0;
  for (int i = t; i < b; i += 256) acc += btot[i];   // bstart = sum btot[<b]
  red[t] = acc;
  __syncthreads();
  for (int off = 128; off > 0; off >>= 1) {
    if (t < off) red[t] += red[t + off];
    __syncthreads();
  }
  if (t == 0) s_start = red[0];
  __syncthreads();
  int bstart = s_start, bend = bstart + btot[b];
  int node0 = b << 8, nn = min(N - node0, 256);
  cnt[t] = 0;
  __syncthreads();
  for (int j = bstart + t; j < bend; j += 256)
    atomicAdd(&cnt[epairs[j].y - node0], 1);         // LDS atomic
  __syncthreads();
  int c = cnt[t];
  red[t] = c;
  __syncthreads();
  for (int off = 1; off < 256; off <<= 1) {          // inclusive scan
    int v = (t >= off) ? red[t - off] : 0;
    __syncthreads();
    red[t] += v;
    __syncthreads();
  }
  int excl = red[t] - c;
  if (t < nn) {
    rowp[node0 + t] = bstart + excl;
    dinv[node0 + t] = 1.0f / sqrtf((float)(c + 1));  // +1 self loop
    cur2[t] = bstart + excl;
  }
  __syncthreads();
  for (int j = bstart + t; j < bend; j += 256) {
    int2 p = epairs[j];
    int pos = atomicAdd(&cur2[p.y - node0], 1);      // LDS atomic
    csr[pos] = p.x;                                  // ~16KB window: L2-local
  }
  if (b == NB - 1 && t == 0) rowp[N] = bend;
}

// --- gemm1 (MFMA): xw1 = x @ W1, bf16 out ----------------------------------
__global__ __launch_bounds__(256) void k_gemm1(const void* __restrict__ x,
                                               const unsigned short* __restrict__ w1t,
                                               unsigned short* __restrict__ xw1,
                                               const int* __restrict__ flags, int N) {
  int w = threadIdx.x >> 6, lane = threadIdx.x & 63;
  int m = lane & 15, quad = lane >> 4;
  int r0 = blockIdx.x * 64 + w * 16;
  int rr = r0 + m; if (rr >= N) rr = N - 1;
  int f32 = flags[0];
  short8 A[4];
  if (f32) {
    const float* xf = (const float*)x + (size_t)rr * IN_F;
#pragma unroll
    for (int ks = 0; ks < 4; ++ks) {
      const float* p = xf + ks * 32 + quad * 8;
      f32x4 u0 = __builtin_nontemporal_load((const f32x4*)p);
      f32x4 u1 = __builtin_nontemporal_load((const f32x4*)(p + 4));
      short8 a;
#pragma unroll
      for (int j = 0; j < 4; ++j) { a[j] = (short)f2bf(u0[j]); a[4 + j] = (short)f2bf(u1[j]); }
      A[ks] = a;
    }
  } else {
    const unsigned short* xb = (const unsigned short*)x + (size_t)rr * IN_F;
#pragma unroll
    for (int ks = 0; ks < 4; ++ks)
      A[ks] = __builtin_nontemporal_load((const short8*)(xb + ks * 32 + quad * 8));
  }
#pragma unroll
  for (int nt = 0; nt < 4; ++nt) {
    f32x4 acc = {0.f, 0.f, 0.f, 0.f};
#pragma unroll
    for (int ks = 0; ks < 4; ++ks) {
      short8 Bf = *(const short8*)(w1t + (nt * 16 + m) * IN_F + ks * 32 + quad * 8);
      acc = __builtin_amdgcn_mfma_f32_16x16x32_bf16(A[ks], Bf, acc, 0, 0, 0);
    }
#pragma unroll
    for (int reg = 0; reg < 4; ++reg) {
      int row = r0 + quad * 4 + reg;
      if (row < N) xw1[(size_t)row * HID_F + nt * 16 + m] = f2bf(acc[reg]);
    }
  }
}

// --- gather1: h = relu(b1 + dv*(dv*xw1[v] + sum dinv[s]*xw1[s])), bf16 out -
__global__ __launch_bounds__(256) void k_gather1(const int* __restrict__ row_ptr,
                                                 const int* __restrict__ csr_src,
                                                 const float* __restrict__ dinv,
                                                 const unsigned short* __restrict__ xw1,
                                                 const void* __restrict__ b1,
                                                 unsigned short* __restrict__ h,
                                                 const int* __restrict__ flags, int N) {
  int v = blockIdx.x * 4 + (threadIdx.x >> 6);
  if (v >= N) return;
  int lane = threadIdx.x & 63;
  int sub = lane >> 3, l8 = lane & 7;
  int start = row_ptr[v], end = row_ptr[v + 1];
  float a[8] = {0.f,0.f,0.f,0.f,0.f,0.f,0.f,0.f};
  for (int j = start + sub; j < end; j += 8) {
    int s = __builtin_nontemporal_load(csr_src + j);   // sequential stream
    float ds = dinv[s];
    bfx8 wv = *(const bfx8*)(xw1 + (size_t)s * HID_F + l8 * 8);
#pragma unroll
    for (int q = 0; q < 8; ++q) a[q] += ds * bf2f(wv[q]);
  }
#pragma unroll
  for (int q = 0; q < 8; ++q) {
    a[q] += __shfl_xor(a[q], 8);
    a[q] += __shfl_xor(a[q], 16);
    a[q] += __shfl_xor(a[q], 32);
  }
  if (sub == 0) {
    float dv = dinv[v];
    bfx8 sw = *(const bfx8*)(xw1 + (size_t)v * HID_F + l8 * 8);
    int f32 = flags[0];
    bfx8 r;
#pragma unroll
    for (int q = 0; q < 8; ++q) {
      float val = ldf(b1, l8 * 8 + q, f32) + dv * (dv * bf2f(sw[q]) + a[q]);
      r[q] = f2bf(fmaxf(val, 0.f));
    }
    *(bfx8*)(h + (size_t)v * HID_F + l8 * 8) = r;
  }
}

// --- gemm2 (MFMA): xw2 = h @ W2, bf16 out ----------------------------------
__global__ __launch_bounds__(256) void k_gemm2(const unsigned short* __restrict__ h,
                                               const unsigned short* __restrict__ w2t,
                                               unsigned short* __restrict__ xw2, int N) {
  int w = threadIdx.x >> 6, lane = threadIdx.x & 63;
  int m = lane & 15, quad = lane >> 4;
  int r0 = blockIdx.x * 64 + w * 16;
  int rr = r0 + m; if (rr >= N) rr = N - 1;
  const unsigned short* hb = h + (size_t)rr * HID_F;
  short8 A[2];
#pragma unroll
  for (int ks = 0; ks < 2; ++ks)
    A[ks] = *(const short8*)(hb + ks * 32 + quad * 8);
#pragma unroll
  for (int nt = 0; nt < 2; ++nt) {
    f32x4 acc = {0.f, 0.f, 0.f, 0.f};
#pragma unroll
    for (int ks = 0; ks < 2; ++ks) {
      short8 Bf = *(const short8*)(w2t + (nt * 16 + m) * HID_F + ks * 32 + quad * 8);
      acc = __builtin_amdgcn_mfma_f32_16x16x32_bf16(A[ks], Bf, acc, 0, 0, 0);
    }
#pragma unroll
    for (int reg = 0; reg < 4; ++reg) {
      int row = r0 + quad * 4 + reg;
      if (row < N) xw2[(size_t)row * OUT_F + nt * 16 + m] = f2bf(acc[reg]);
    }
  }
}

// --- gather2: z = b2 + dv*(dv*xw2[v] + sum dinv[s]*xw2[s]), bf16 out -------
__global__ __launch_bounds__(256) void k_gather2(const int* __restrict__ row_ptr,
                                                 const int* __restrict__ csr_src,
                                                 const float* __restrict__ dinv,
                                                 const unsigned short* __restrict__ xw2,
                                                 const void* __restrict__ b2,
                                                 unsigned short* __restrict__ z,
                                                 const int* __restrict__ flags, int N) {
  int v = blockIdx.x * 4 + (threadIdx.x >> 6);
  if (v >= N) return;
  int lane = threadIdx.x & 63;
  int sub = lane >> 3, l8 = lane & 7;
  int start = row_ptr[v], end = row_ptr[v + 1];
  float a[4] = {0.f, 0.f, 0.f, 0.f};
  for (int j = start + sub; j < end; j += 8) {
    int s = __builtin_nontemporal_load(csr_src + j);   // sequential stream
    float ds = dinv[s];
    bfx4 wv = *(const bfx4*)(xw2 + (size_t)s * OUT_F + l8 * 4);
#pragma unroll
    for (int q = 0; q < 4; ++q) a[q] += ds * bf2f(wv[q]);
  }
#pragma unroll
  for (int q = 0; q < 4; ++q) {
    a[q] += __shfl_xor(a[q], 8);
    a[q] += __shfl_xor(a[q], 16);
    a[q] += __shfl_xor(a[q], 32);
  }
  if (sub == 0) {
    float dv = dinv[v];
    bfx4 sw = *(const bfx4*)(xw2 + (size_t)v * OUT_F + l8 * 4);
    int f32 = flags[0];
    bfx4 r;
#pragma unroll
    for (int q = 0; q < 4; ++q)
      r[q] = f2bf(ldf(b2, l8 * 4 + q, f32) + dv * (dv * bf2f(sw[q]) + a[q]));
    *(bfx4*)(z + (size_t)v * OUT_F + l8 * 4) = r;
  }
}

// --- decode + edge copy: 4 lanes/edge, bf16 z, f32 accumulate --------------
// z rows are 64B and 64B-aligned now: one line per endpoint (was 2).
__global__ __launch_bounds__(256) void k_decode(const void* __restrict__ pe,
                                                const void* __restrict__ ne,
                                                const unsigned short* __restrict__ z,
                                                float* __restrict__ out,
                                                const int* __restrict__ flags,
                                                int E, int N) {
  int tid = blockIdx.x * 256 + threadIdx.x;
  int e = tid >> 2, g = tid & 3;
  int twoE = 2 * E;
  if (e >= twoE) return;
  int i64 = flags[1];
  int src, dst;
  if (e < E) { src = ldi_nt(pe, e, i64); dst = ldi_nt(pe, (long long)E + e, i64); }
  else       { src = ldi_nt(ne, e - E, i64); dst = ldi_nt(ne, e, i64); }
  if (g == 1) __builtin_nontemporal_store((float)src, out + twoE + e);      // row0
  if (g == 2) __builtin_nontemporal_store((float)dst, out + 2 * twoE + e);  // row1
  int cs = clampN(src, N), cd = clampN(dst, N);
  bfx8 a = *(const bfx8*)(z + (size_t)cs * OUT_F + g * 8);
  bfx8 b = *(const bfx8*)(z + (size_t)cd * OUT_F + g * 8);
  float s = 0.f;
#pragma unroll
  for (int q = 0; q < 8; ++q) s += bf2f(a[q]) * bf2f(b[q]);
  s += __shfl_xor(s, 1);
  s += __shfl_xor(s, 2);
  s = fminf(fmaxf(s, -500.0f), 500.0f);          // insurance rail (R2 notes)
  if (g == 0) __builtin_nontemporal_store(s, out + e);
}

extern "C" void kernel_launch(void* const* d_in, const int* in_sizes, int n_in,
                              void* d_out, int out_size, void* d_ws, size_t ws_size,
                              hipStream_t stream) {
  const void* x  = d_in[0];
  const void* W1 = d_in[1];
  const void* b1 = d_in[2];
  const void* W2 = d_in[3];
  const void* b2 = d_in[4];
  const void* pe = d_in[5];
  const void* ne = d_in[6];
  int N = in_sizes[0] / IN_F;       // 100000
  int E = in_sizes[5] / 2;          // 1600000
  int NB = (N + 255) >> 8;          // 391 buckets
  int CH = (E + NA - 1) / NA;       // 8000 edges/chunk

  int*   ip    = (int*)d_ws;
  float* ws    = (float*)d_ws;
  int*   flags = ip + OFF_FLAGS;
  unsigned short* w1t = (unsigned short*)(ip + OFF_W1T);
  unsigned short* w2t = (unsigned short*)(ip + OFF_W2T);
  int*   hist  = ip + OFF_HIST;
  int*   btot  = ip + OFF_BTOT;
  int*   rowp  = ip + OFF_ROWP;
  float* dinv  = ws + OFF_DINV;
  int2*  epairs= (int2*)(ip + OFF_EPAIRS);
  int*   csr   = ip + OFF_CSR;
  unsigned short* xw1 = (unsigned short*)(ip + OFF_XW1);
  unsigned short* h   = (unsigned short*)(ip + OFF_H);
  unsigned short* xw2 = (unsigned short*)(ip + OFF_XW2);
  unsigned short* zz  = (unsigned short*)(ip + OFF_Z);
  float* out   = (float*)d_out;

  k_prep<<<1, 256, 0, stream>>>(x, pe, W1, W2, flags, w1t, w2t);
  k_hist<<<NA, 256, 0, stream>>>(pe, hist, flags, E, N, CH);
  k_colscan<<<NB, 256, 0, stream>>>(hist, btot);
  k_scatter<<<NA, 256, 0, stream>>>(pe, hist, btot, epairs, flags, E, N, NB, CH);
  k_bsort<<<NB, 256, 0, stream>>>(epairs, btot, rowp, dinv, csr, N, NB);
  k_gemm1<<<(N + 63) / 64, 256, 0, stream>>>(x, w1t, xw1, flags, N);
  k_gather1<<<(N + 3) / 4, 256, 0, stream>>>(rowp, csr, dinv, xw1, b1, h, flags, N);
  k_gemm2<<<(N + 63) / 64, 256, 0, stream>>>(h, w2t, xw2, N);
  k_gather2<<<(N + 3) / 4, 256, 0, stream>>>(rowp, csr, dinv, xw2, b2, zz, flags, N);
  k_decode<<<(2 * E * 4 + 255) / 256, 256, 0, stream>>>(pe, ne, zz, out, flags, E, N);
}

// Round 5
// 384.136 us; speedup vs baseline: 1.4543x; 1.0084x over previous
//
#include <hip/hip_runtime.h>
#include <hip/hip_bf16.h>

// ---------------------------------------------------------------------------
// GCN link predictor, R13: R12 + 4-edge ILP decode (latency-exposure fix).
// R12 post-mortem: 64B-aligned tables confirmed (decode FETCH 253->163MB,
// dur 80->64us). Remaining decode profile = latency-bound: VALUBusy 37%,
// occ 73%, HBM 41%, L2 BW <<peak -- ~4 VMEM in flight/wave can't cover the
// ~400cyc avg z-line latency (27% HBM miss). Fix: 4 edges per lane-quad,
// phase-batched loads (8 index + 8 z-row loads in flight/lane), then
// compute. Bit-identical numerics; decode grid 50000->12500 blocks.
//   h = relu(b1 + dv*(dv*xw1[v] + sum dinv[s]*xw1[s])),  xw1 = x @ W1 (MFMA)
//   z = b2 + dv*(dv*xw2[v] + sum dinv[s]*xw2[s]),        xw2 = h @ W2 (MFMA)
//   logits[e] = dot(z[src], z[dst]) over [pos; neg]
// Output: FLOAT32 [logits(2E)][edge row0(2E)][row1(2E)] (established R2).
// ---------------------------------------------------------------------------

#define IN_F  128
#define HID_F 64
#define OUT_F 32
#define NA    200      // edge-chunk blocks for hist/scatter
#define NBS   512      // histogram stride (>= NB=391 buckets of 256 nodes)
#define DEC_U 4        // edges per lane-quad in decode

// workspace element offsets (4-byte units); all table bases 128B-aligned.
// N=100000, E=1600000; end = 14,708,096 ints = 58.83 MB.
#define OFF_FLAGS   0          // 2 ints
#define OFF_W1T     32         // 8192 bf16 = 4096 ints
#define OFF_W2T     4128       // 2048 bf16 = 1024 ints
#define OFF_HIST    5152       // NA*NBS = 102400 ints
#define OFF_BTOT    107552     // 512 ints
#define OFF_ROWP    108064     // N+1 ints (-> 208065)
#define OFF_DINV    208096     // N floats
#define OFF_EPAIRS  308096     // 2E ints (int2 pairs; byte%8==0)
#define OFF_CSR     3508096    // E ints
#define OFF_XW1     5108096    // N*64 bf16 = 3.2M ints (base byte%128==0)
#define OFF_H       8308096    // N*64 bf16
#define OFF_XW2     11508096   // N*32 bf16 = 1.6M ints
#define OFF_Z       13108096   // N*32 bf16 -> end 14708096

typedef short short8 __attribute__((ext_vector_type(8)));
typedef float f32x4  __attribute__((ext_vector_type(4)));
typedef unsigned short bfx8 __attribute__((ext_vector_type(8)));
typedef unsigned short bfx4 __attribute__((ext_vector_type(4)));

__device__ __forceinline__ float ldf(const void* p, int i, int f32) {
  if (f32) return ((const float*)p)[i];
  unsigned int w = ((unsigned int)((const unsigned short*)p)[i]) << 16;
  return __uint_as_float(w);
}
__device__ __forceinline__ int ldi(const void* p, long long i, int i64) {
  if (i64) return (int)((const long long*)p)[i];
  return ((const int*)p)[i];
}
// non-temporal index load: single-use streams, keep out of L2
__device__ __forceinline__ int ldi_nt(const void* p, long long i, int i64) {
  if (i64) return (int)__builtin_nontemporal_load(((const long long*)p) + i);
  return __builtin_nontemporal_load(((const int*)p) + i);
}
__device__ __forceinline__ int clampN(int v, int N) {
  unsigned u = (unsigned)v;
  return (u < (unsigned)N) ? v : 0;
}
__device__ __forceinline__ unsigned short f2bf(float f) {   // RNE f32->bf16
  unsigned u = __float_as_uint(f);
  return (unsigned short)((u + 0x7FFFu + ((u >> 16) & 1u)) >> 16);
}
__device__ __forceinline__ float bf2f(unsigned short h) {
  return __uint_as_float(((unsigned)h) << 16);
}

// --- prep (grid 1): detect dtypes + transpose weights ----------------------
__global__ __launch_bounds__(256) void k_prep(const void* __restrict__ x,
                                              const void* __restrict__ pe,
                                              const void* __restrict__ W1,
                                              const void* __restrict__ W2,
                                              int* __restrict__ flags,
                                              unsigned short* __restrict__ w1t,
                                              unsigned short* __restrict__ w2t) {
  __shared__ int s_big, s_nzodd;
  int t = threadIdx.x;
  if (t == 0) { s_big = 0; s_nzodd = 0; }
  __syncthreads();
  int nbig = 0, nz = 0;
  const unsigned short* xb = (const unsigned short*)x;
  for (int i = t; i < 4096; i += 256) {
    int ex = (xb[i] >> 7) & 0xFF;
    if (ex >= 147) nbig++;               // |v|>=2^20 impossible for N(0,1) bf16
  }
  const int* pi = (const int*)pe;
  for (int i = t; i < 2048; i += 256) {
    if (pi[2 * i + 1] != 0) nz++;        // int64 hi-words all zero
  }
  atomicAdd(&s_big, nbig);
  atomicAdd(&s_nzodd, nz);
  __syncthreads();
  int f32 = (s_big > 400) ? 1 : 0;
  if (t == 0) {
    flags[0] = f32;
    flags[1] = (s_nzodd < 100) ? 1 : 0;
  }
  for (int i = t; i < HID_F * IN_F; i += 256) {   // W1T[n*128+k] = W1[k*64+n]
    int n = i >> 7, k = i & 127;
    w1t[i] = f2bf(ldf(W1, k * HID_F + n, f32));
  }
  for (int i = t; i < OUT_F * HID_F; i += 256) {  // W2T[n*64+k] = W2[k*32+n]
    int n = i >> 6, k = i & 63;
    w2t[i] = f2bf(ldf(W2, k * OUT_F + n, f32));
  }
}

// --- CSR build pass 1: per-chunk LDS histogram over buckets ---------------
__global__ __launch_bounds__(256) void k_hist(const void* __restrict__ pe,
                                              int* __restrict__ histmat,
                                              const int* __restrict__ flags,
                                              int E, int N, int CH) {
  __shared__ int hist[NBS];
  int t = threadIdx.x;
  for (int i = t; i < NBS; i += 256) hist[i] = 0;
  __syncthreads();
  int i64 = flags[1];
  int base = blockIdx.x * CH, end = min(base + CH, E);
  for (int e = base + t; e < end; e += 256) {
    int dst = clampN(ldi_nt(pe, (long long)E + e, i64), N);
    atomicAdd(&hist[dst >> 8], 1);       // LDS atomic
  }
  __syncthreads();
  for (int i = t; i < NBS; i += 256) histmat[blockIdx.x * NBS + i] = hist[i];
}

// --- pass 2: per-bucket column exclusive scan + bucket totals --------------
__global__ __launch_bounds__(256) void k_colscan(int* __restrict__ histmat,
                                                 int* __restrict__ btot) {
  __shared__ int a[256];
  int b = blockIdx.x, t = threadIdx.x;
  int h = (t < NA) ? histmat[t * NBS + b] : 0;
  a[t] = h;
  __syncthreads();
  for (int off = 1; off < 256; off <<= 1) {
    int v = (t >= off) ? a[t - off] : 0;
    __syncthreads();
    a[t] += v;
    __syncthreads();
  }
  if (t < NA) histmat[t * NBS + b] = a[t] - h;   // exclusive within column
  if (t == 255) btot[b] = a[255];
}

// --- pass 3: scatter pairs into bucket-sorted order (LDS cursors only) -----
__global__ __launch_bounds__(256) void k_scatter(const void* __restrict__ pe,
                                                 const int* __restrict__ histmat,
                                                 const int* __restrict__ btot,
                                                 int2* __restrict__ epairs,
                                                 const int* __restrict__ flags,
                                                 int E, int N, int NB, int CH) {
  __shared__ int sc[NBS];
  __shared__ int cur[NBS];
  int t = threadIdx.x;
  int o0 = (t < NB) ? btot[t] : 0;
  int o1 = (t + 256 < NB) ? btot[t + 256] : 0;
  sc[t] = o0; sc[t + 256] = o1;
  __syncthreads();
  for (int off = 1; off < NBS; off <<= 1) {      // Hillis-Steele, 2 slots/thread
    int v0 = (t >= off) ? sc[t - off] : 0;
    int v1 = (t + 256 >= off) ? sc[t + 256 - off] : 0;
    __syncthreads();
    sc[t] += v0; sc[t + 256] += v1;
    __syncthreads();
  }
  const int* row = histmat + blockIdx.x * NBS;   // contiguous row
  cur[t]       = sc[t] - o0 + row[t];            // bucket base + block cursor
  cur[t + 256] = sc[t + 256] - o1 + row[t + 256];
  __syncthreads();
  int i64 = flags[1];
  int base = blockIdx.x * CH, end = min(base + CH, E);
  for (int e = base + t; e < end; e += 256) {
    int src = clampN(ldi_nt(pe, e, i64), N);
    int dst = clampN(ldi_nt(pe, (long long)E + e, i64), N);
    int pos = atomicAdd(&cur[dst >> 8], 1);      // LDS atomic
    epairs[pos] = make_int2(src, dst);
  }
}

// --- pass 4: per-bucket counting sort -> csr; emits rowp + dinv ------------
__global__ __launch_bounds__(256) void k_bsort(const int2* __restrict__ epairs,
                                               const int* __restrict__ btot,
                                               int* __restrict__ rowp,
                                               float* __restrict__ dinv,
                                               int* __restrict__ csr,
                                               int N, int NB) {
  __shared__ int red[256];
  __shared__ int cnt[256];
  __shared__ int cur2[256];
  __shared__ int s_start;
  int b = blockIdx.x, t = threadIdx.x;
  int acc = 0;
  for (int i = t; i < b; i += 256) acc += btot[i];   // bstart = sum btot[<b]
  red[t] = acc;
  __syncthreads();
  for (int off = 128; off > 0; off >>= 1) {
    if (t < off) red[t] += red[t + off];
    __syncthreads();
  }
  if (t == 0) s_start = red[0];
  __syncthreads();
  int bstart = s_start, bend = bstart + btot[b];
  int node0 = b << 8, nn = min(N - node0, 256);
  cnt[t] = 0;
  __syncthreads();
  for (int j = bstart + t; j < bend; j += 256)
    atomicAdd(&cnt[epairs[j].y - node0], 1);         // LDS atomic
  __syncthreads();
  int c = cnt[t];
  red[t] = c;
  __syncthreads();
  for (int off = 1; off < 256; off <<= 1) {          // inclusive scan
    int v = (t >= off) ? red[t - off] : 0;
    __syncthreads();
    red[t] += v;
    __syncthreads();
  }
  int excl = red[t] - c;
  if (t < nn) {
    rowp[node0 + t] = bstart + excl;
    dinv[node0 + t] = 1.0f / sqrtf((float)(c + 1));  // +1 self loop
    cur2[t] = bstart + excl;
  }
  __syncthreads();
  for (int j = bstart + t; j < bend; j += 256) {
    int2 p = epairs[j];
    int pos = atomicAdd(&cur2[p.y - node0], 1);      // LDS atomic
    csr[pos] = p.x;                                  // ~16KB window: L2-local
  }
  if (b == NB - 1 && t == 0) rowp[N] = bend;
}

// --- gemm1 (MFMA): xw1 = x @ W1, bf16 out ----------------------------------
__global__ __launch_bounds__(256) void k_gemm1(const void* __restrict__ x,
                                               const unsigned short* __restrict__ w1t,
                                               unsigned short* __restrict__ xw1,
                                               const int* __restrict__ flags, int N) {
  int w = threadIdx.x >> 6, lane = threadIdx.x & 63;
  int m = lane & 15, quad = lane >> 4;
  int r0 = blockIdx.x * 64 + w * 16;
  int rr = r0 + m; if (rr >= N) rr = N - 1;
  int f32 = flags[0];
  short8 A[4];
  if (f32) {
    const float* xf = (const float*)x + (size_t)rr * IN_F;
#pragma unroll
    for (int ks = 0; ks < 4; ++ks) {
      const float* p = xf + ks * 32 + quad * 8;
      f32x4 u0 = __builtin_nontemporal_load((const f32x4*)p);
      f32x4 u1 = __builtin_nontemporal_load((const f32x4*)(p + 4));
      short8 a;
#pragma unroll
      for (int j = 0; j < 4; ++j) { a[j] = (short)f2bf(u0[j]); a[4 + j] = (short)f2bf(u1[j]); }
      A[ks] = a;
    }
  } else {
    const unsigned short* xb = (const unsigned short*)x + (size_t)rr * IN_F;
#pragma unroll
    for (int ks = 0; ks < 4; ++ks)
      A[ks] = __builtin_nontemporal_load((const short8*)(xb + ks * 32 + quad * 8));
  }
#pragma unroll
  for (int nt = 0; nt < 4; ++nt) {
    f32x4 acc = {0.f, 0.f, 0.f, 0.f};
#pragma unroll
    for (int ks = 0; ks < 4; ++ks) {
      short8 Bf = *(const short8*)(w1t + (nt * 16 + m) * IN_F + ks * 32 + quad * 8);
      acc = __builtin_amdgcn_mfma_f32_16x16x32_bf16(A[ks], Bf, acc, 0, 0, 0);
    }
#pragma unroll
    for (int reg = 0; reg < 4; ++reg) {
      int row = r0 + quad * 4 + reg;
      if (row < N) xw1[(size_t)row * HID_F + nt * 16 + m] = f2bf(acc[reg]);
    }
  }
}

// --- gather1: h = relu(b1 + dv*(dv*xw1[v] + sum dinv[s]*xw1[s])), bf16 out -
__global__ __launch_bounds__(256) void k_gather1(const int* __restrict__ row_ptr,
                                                 const int* __restrict__ csr_src,
                                                 const float* __restrict__ dinv,
                                                 const unsigned short* __restrict__ xw1,
                                                 const void* __restrict__ b1,
                                                 unsigned short* __restrict__ h,
                                                 const int* __restrict__ flags, int N) {
  int v = blockIdx.x * 4 + (threadIdx.x >> 6);
  if (v >= N) return;
  int lane = threadIdx.x & 63;
  int sub = lane >> 3, l8 = lane & 7;
  int start = row_ptr[v], end = row_ptr[v + 1];
  float a[8] = {0.f,0.f,0.f,0.f,0.f,0.f,0.f,0.f};
  for (int j = start + sub; j < end; j += 8) {
    int s = __builtin_nontemporal_load(csr_src + j);   // sequential stream
    float ds = dinv[s];
    bfx8 wv = *(const bfx8*)(xw1 + (size_t)s * HID_F + l8 * 8);
#pragma unroll
    for (int q = 0; q < 8; ++q) a[q] += ds * bf2f(wv[q]);
  }
#pragma unroll
  for (int q = 0; q < 8; ++q) {
    a[q] += __shfl_xor(a[q], 8);
    a[q] += __shfl_xor(a[q], 16);
    a[q] += __shfl_xor(a[q], 32);
  }
  if (sub == 0) {
    float dv = dinv[v];
    bfx8 sw = *(const bfx8*)(xw1 + (size_t)v * HID_F + l8 * 8);
    int f32 = flags[0];
    bfx8 r;
#pragma unroll
    for (int q = 0; q < 8; ++q) {
      float val = ldf(b1, l8 * 8 + q, f32) + dv * (dv * bf2f(sw[q]) + a[q]);
      r[q] = f2bf(fmaxf(val, 0.f));
    }
    *(bfx8*)(h + (size_t)v * HID_F + l8 * 8) = r;
  }
}

// --- gemm2 (MFMA): xw2 = h @ W2, bf16 out ----------------------------------
__global__ __launch_bounds__(256) void k_gemm2(const unsigned short* __restrict__ h,
                                               const unsigned short* __restrict__ w2t,
                                               unsigned short* __restrict__ xw2, int N) {
  int w = threadIdx.x >> 6, lane = threadIdx.x & 63;
  int m = lane & 15, quad = lane >> 4;
  int r0 = blockIdx.x * 64 + w * 16;
  int rr = r0 + m; if (rr >= N) rr = N - 1;
  const unsigned short* hb = h + (size_t)rr * HID_F;
  short8 A[2];
#pragma unroll
  for (int ks = 0; ks < 2; ++ks)
    A[ks] = *(const short8*)(hb + ks * 32 + quad * 8);
#pragma unroll
  for (int nt = 0; nt < 2; ++nt) {
    f32x4 acc = {0.f, 0.f, 0.f, 0.f};
#pragma unroll
    for (int ks = 0; ks < 2; ++ks) {
      short8 Bf = *(const short8*)(w2t + (nt * 16 + m) * HID_F + ks * 32 + quad * 8);
      acc = __builtin_amdgcn_mfma_f32_16x16x32_bf16(A[ks], Bf, acc, 0, 0, 0);
    }
#pragma unroll
    for (int reg = 0; reg < 4; ++reg) {
      int row = r0 + quad * 4 + reg;
      if (row < N) xw2[(size_t)row * OUT_F + nt * 16 + m] = f2bf(acc[reg]);
    }
  }
}

// --- gather2: z = b2 + dv*(dv*xw2[v] + sum dinv[s]*xw2[s]), bf16 out -------
__global__ __launch_bounds__(256) void k_gather2(const int* __restrict__ row_ptr,
                                                 const int* __restrict__ csr_src,
                                                 const float* __restrict__ dinv,
                                                 const unsigned short* __restrict__ xw2,
                                                 const void* __restrict__ b2,
                                                 unsigned short* __restrict__ z,
                                                 const int* __restrict__ flags, int N) {
  int v = blockIdx.x * 4 + (threadIdx.x >> 6);
  if (v >= N) return;
  int lane = threadIdx.x & 63;
  int sub = lane >> 3, l8 = lane & 7;
  int start = row_ptr[v], end = row_ptr[v + 1];
  float a[4] = {0.f, 0.f, 0.f, 0.f};
  for (int j = start + sub; j < end; j += 8) {
    int s = __builtin_nontemporal_load(csr_src + j);   // sequential stream
    float ds = dinv[s];
    bfx4 wv = *(const bfx4*)(xw2 + (size_t)s * OUT_F + l8 * 4);
#pragma unroll
    for (int q = 0; q < 4; ++q) a[q] += ds * bf2f(wv[q]);
  }
#pragma unroll
  for (int q = 0; q < 4; ++q) {
    a[q] += __shfl_xor(a[q], 8);
    a[q] += __shfl_xor(a[q], 16);
    a[q] += __shfl_xor(a[q], 32);
  }
  if (sub == 0) {
    float dv = dinv[v];
    bfx4 sw = *(const bfx4*)(xw2 + (size_t)v * OUT_F + l8 * 4);
    int f32 = flags[0];
    bfx4 r;
#pragma unroll
    for (int q = 0; q < 4; ++q)
      r[q] = f2bf(ldf(b2, l8 * 4 + q, f32) + dv * (dv * bf2f(sw[q]) + a[q]));
    *(bfx4*)(z + (size_t)v * OUT_F + l8 * 4) = r;
  }
}

// --- decode: 4 lanes/edge x DEC_U edges/quad, phase-batched loads ----------
// Phase 1: issue all 2*DEC_U index loads. Phase 2: issue all 2*DEC_U z-row
// loads (16B/lane each). Phase 3: compute + store. 4x MLP of R12.
__global__ __launch_bounds__(256) void k_decode(const void* __restrict__ pe,
                                                const void* __restrict__ ne,
                                                const unsigned short* __restrict__ z,
                                                float* __restrict__ out,
                                                const int* __restrict__ flags,
                                                int E, int N, int Q) {
  int q = blockIdx.x * 64 + (threadIdx.x >> 2);  // global quad id
  int g = threadIdx.x & 3;
  int twoE = 2 * E;
  int i64 = flags[1];
  int ee[DEC_U], src[DEC_U], dst[DEC_U];
  bool ok[DEC_U];
#pragma unroll
  for (int u = 0; u < DEC_U; ++u) {              // phase 1: index loads
    int e = q + u * Q;
    ee[u] = e; ok[u] = (e < twoE);
    src[u] = 0; dst[u] = 0;
    if (ok[u]) {
      if (e < E) { src[u] = ldi_nt(pe, e, i64); dst[u] = ldi_nt(pe, (long long)E + e, i64); }
      else       { src[u] = ldi_nt(ne, e - E, i64); dst[u] = ldi_nt(ne, e, i64); }
    }
  }
  bfx8 av[DEC_U], bv[DEC_U];
#pragma unroll
  for (int u = 0; u < DEC_U; ++u) {              // phase 2: z-row loads
    int cs = clampN(src[u], N), cd = clampN(dst[u], N);
    av[u] = *(const bfx8*)(z + (size_t)cs * OUT_F + g * 8);
    bv[u] = *(const bfx8*)(z + (size_t)cd * OUT_F + g * 8);
  }
#pragma unroll
  for (int u = 0; u < DEC_U; ++u) {              // phase 3: compute + store
    if (!ok[u]) continue;
    int e = ee[u];
    if (g == 1) __builtin_nontemporal_store((float)src[u], out + twoE + e);
    if (g == 2) __builtin_nontemporal_store((float)dst[u], out + 2 * twoE + e);
    float s = 0.f;
#pragma unroll
    for (int k = 0; k < 8; ++k) s += bf2f(av[u][k]) * bf2f(bv[u][k]);
    s += __shfl_xor(s, 1);
    s += __shfl_xor(s, 2);
    s = fminf(fmaxf(s, -500.0f), 500.0f);        // insurance rail (R2 notes)
    if (g == 0) __builtin_nontemporal_store(s, out + e);
  }
}

extern "C" void kernel_launch(void* const* d_in, const int* in_sizes, int n_in,
                              void* d_out, int out_size, void* d_ws, size_t ws_size,
                              hipStream_t stream) {
  const void* x  = d_in[0];
  const void* W1 = d_in[1];
  const void* b1 = d_in[2];
  const void* W2 = d_in[3];
  const void* b2 = d_in[4];
  const void* pe = d_in[5];
  const void* ne = d_in[6];
  int N = in_sizes[0] / IN_F;       // 100000
  int E = in_sizes[5] / 2;          // 1600000
  int NB = (N + 255) >> 8;          // 391 buckets
  int CH = (E + NA - 1) / NA;       // 8000 edges/chunk

  int*   ip    = (int*)d_ws;
  float* ws    = (float*)d_ws;
  int*   flags = ip + OFF_FLAGS;
  unsigned short* w1t = (unsigned short*)(ip + OFF_W1T);
  unsigned short* w2t = (unsigned short*)(ip + OFF_W2T);
  int*   hist  = ip + OFF_HIST;
  int*   btot  = ip + OFF_BTOT;
  int*   rowp  = ip + OFF_ROWP;
  float* dinv  = ws + OFF_DINV;
  int2*  epairs= (int2*)(ip + OFF_EPAIRS);
  int*   csr   = ip + OFF_CSR;
  unsigned short* xw1 = (unsigned short*)(ip + OFF_XW1);
  unsigned short* h   = (unsigned short*)(ip + OFF_H);
  unsigned short* xw2 = (unsigned short*)(ip + OFF_XW2);
  unsigned short* zz  = (unsigned short*)(ip + OFF_Z);
  float* out   = (float*)d_out;

  k_prep<<<1, 256, 0, stream>>>(x, pe, W1, W2, flags, w1t, w2t);
  k_hist<<<NA, 256, 0, stream>>>(pe, hist, flags, E, N, CH);
  k_colscan<<<NB, 256, 0, stream>>>(hist, btot);
  k_scatter<<<NA, 256, 0, stream>>>(pe, hist, btot, epairs, flags, E, N, NB, CH);
  k_bsort<<<NB, 256, 0, stream>>>(epairs, btot, rowp, dinv, csr, N, NB);
  k_gemm1<<<(N + 63) / 64, 256, 0, stream>>>(x, w1t, xw1, flags, N);
  k_gather1<<<(N + 3) / 4, 256, 0, stream>>>(rowp, csr, dinv, xw1, b1, h, flags, N);
  k_gemm2<<<(N + 63) / 64, 256, 0, stream>>>(h, w2t, xw2, N);
  k_gather2<<<(N + 3) / 4, 256, 0, stream>>>(rowp, csr, dinv, xw2, b2, zz, flags, N);
  int edges_per_block = 64 * DEC_U;                       // 256
  int DB = (2 * E + edges_per_block - 1) / edges_per_block;  // 12500
  k_decode<<<DB, 256, 0, stream>>>(pe, ne, zz, out, flags, E, N, DB * 64);
}

// Round 6
// 382.220 us; speedup vs baseline: 1.4616x; 1.0050x over previous
//
#include <hip/hip_runtime.h>
#include <hip/hip_bf16.h>

// ---------------------------------------------------------------------------
// GCN link predictor, R14: R13 + dinv folded into xw tables at GEMM time.
// R13 post-mortem: decode is at a ~130-150G random-line-requests/s device
// floor (R11 cross-check: L2-hit-only gathers run at the same rate) -- 2
// mandatory lines/edge => ~49us floor, measured 60. Lever moves to gather1
// (60us): ~33% of its line requests are scattered dinv[s] gathers + a
// dependent load in the csr->row chain. Fix: gemm1/gemm2 store pre-scaled
// rows xw1'[s]=dinv[s]*xw1[s] (f32 scale before bf16 store; same rounding
// count), gathers become pure row-sums:
//   h = relu(b1 + dv*(xw1'[v] + sum_s xw1'[s]))
//   z = b2 + dv*(xw2'[v] + sum_s xw2'[s])
//   logits[e] = dot(z[src], z[dst]) over [pos; neg]
// Output: FLOAT32 [logits(2E)][edge row0(2E)][row1(2E)] (established R2).
// ---------------------------------------------------------------------------

#define IN_F  128
#define HID_F 64
#define OUT_F 32
#define NA    200      // edge-chunk blocks for hist/scatter
#define NBS   512      // histogram stride (>= NB=391 buckets of 256 nodes)
#define DEC_U 4        // edges per lane-quad in decode

// workspace element offsets (4-byte units); all table bases 128B-aligned.
// N=100000, E=1600000; end = 14,708,096 ints = 58.83 MB.
#define OFF_FLAGS   0          // 2 ints
#define OFF_W1T     32         // 8192 bf16 = 4096 ints
#define OFF_W2T     4128       // 2048 bf16 = 1024 ints
#define OFF_HIST    5152       // NA*NBS = 102400 ints
#define OFF_BTOT    107552     // 512 ints
#define OFF_ROWP    108064     // N+1 ints (-> 208065)
#define OFF_DINV    208096     // N floats
#define OFF_EPAIRS  308096     // 2E ints (int2 pairs; byte%8==0)
#define OFF_CSR     3508096    // E ints
#define OFF_XW1     5108096    // N*64 bf16 = 3.2M ints (base byte%128==0)
#define OFF_H       8308096    // N*64 bf16
#define OFF_XW2     11508096   // N*32 bf16 = 1.6M ints
#define OFF_Z       13108096   // N*32 bf16 -> end 14708096

typedef short short8 __attribute__((ext_vector_type(8)));
typedef float f32x4  __attribute__((ext_vector_type(4)));
typedef unsigned short bfx8 __attribute__((ext_vector_type(8)));
typedef unsigned short bfx4 __attribute__((ext_vector_type(4)));

__device__ __forceinline__ float ldf(const void* p, int i, int f32) {
  if (f32) return ((const float*)p)[i];
  unsigned int w = ((unsigned int)((const unsigned short*)p)[i]) << 16;
  return __uint_as_float(w);
}
__device__ __forceinline__ int ldi(const void* p, long long i, int i64) {
  if (i64) return (int)((const long long*)p)[i];
  return ((const int*)p)[i];
}
// non-temporal index load: single-use streams, keep out of L2
__device__ __forceinline__ int ldi_nt(const void* p, long long i, int i64) {
  if (i64) return (int)__builtin_nontemporal_load(((const long long*)p) + i);
  return __builtin_nontemporal_load(((const int*)p) + i);
}
__device__ __forceinline__ int clampN(int v, int N) {
  unsigned u = (unsigned)v;
  return (u < (unsigned)N) ? v : 0;
}
__device__ __forceinline__ unsigned short f2bf(float f) {   // RNE f32->bf16
  unsigned u = __float_as_uint(f);
  return (unsigned short)((u + 0x7FFFu + ((u >> 16) & 1u)) >> 16);
}
__device__ __forceinline__ float bf2f(unsigned short h) {
  return __uint_as_float(((unsigned)h) << 16);
}

// --- prep (grid 1): detect dtypes + transpose weights ----------------------
__global__ __launch_bounds__(256) void k_prep(const void* __restrict__ x,
                                              const void* __restrict__ pe,
                                              const void* __restrict__ W1,
                                              const void* __restrict__ W2,
                                              int* __restrict__ flags,
                                              unsigned short* __restrict__ w1t,
                                              unsigned short* __restrict__ w2t) {
  __shared__ int s_big, s_nzodd;
  int t = threadIdx.x;
  if (t == 0) { s_big = 0; s_nzodd = 0; }
  __syncthreads();
  int nbig = 0, nz = 0;
  const unsigned short* xb = (const unsigned short*)x;
  for (int i = t; i < 4096; i += 256) {
    int ex = (xb[i] >> 7) & 0xFF;
    if (ex >= 147) nbig++;               // |v|>=2^20 impossible for N(0,1) bf16
  }
  const int* pi = (const int*)pe;
  for (int i = t; i < 2048; i += 256) {
    if (pi[2 * i + 1] != 0) nz++;        // int64 hi-words all zero
  }
  atomicAdd(&s_big, nbig);
  atomicAdd(&s_nzodd, nz);
  __syncthreads();
  int f32 = (s_big > 400) ? 1 : 0;
  if (t == 0) {
    flags[0] = f32;
    flags[1] = (s_nzodd < 100) ? 1 : 0;
  }
  for (int i = t; i < HID_F * IN_F; i += 256) {   // W1T[n*128+k] = W1[k*64+n]
    int n = i >> 7, k = i & 127;
    w1t[i] = f2bf(ldf(W1, k * HID_F + n, f32));
  }
  for (int i = t; i < OUT_F * HID_F; i += 256) {  // W2T[n*64+k] = W2[k*32+n]
    int n = i >> 6, k = i & 63;
    w2t[i] = f2bf(ldf(W2, k * OUT_F + n, f32));
  }
}

// --- CSR build pass 1: per-chunk LDS histogram over buckets ---------------
__global__ __launch_bounds__(256) void k_hist(const void* __restrict__ pe,
                                              int* __restrict__ histmat,
                                              const int* __restrict__ flags,
                                              int E, int N, int CH) {
  __shared__ int hist[NBS];
  int t = threadIdx.x;
  for (int i = t; i < NBS; i += 256) hist[i] = 0;
  __syncthreads();
  int i64 = flags[1];
  int base = blockIdx.x * CH, end = min(base + CH, E);
  for (int e = base + t; e < end; e += 256) {
    int dst = clampN(ldi_nt(pe, (long long)E + e, i64), N);
    atomicAdd(&hist[dst >> 8], 1);       // LDS atomic
  }
  __syncthreads();
  for (int i = t; i < NBS; i += 256) histmat[blockIdx.x * NBS + i] = hist[i];
}

// --- pass 2: per-bucket column exclusive scan + bucket totals --------------
__global__ __launch_bounds__(256) void k_colscan(int* __restrict__ histmat,
                                                 int* __restrict__ btot) {
  __shared__ int a[256];
  int b = blockIdx.x, t = threadIdx.x;
  int h = (t < NA) ? histmat[t * NBS + b] : 0;
  a[t] = h;
  __syncthreads();
  for (int off = 1; off < 256; off <<= 1) {
    int v = (t >= off) ? a[t - off] : 0;
    __syncthreads();
    a[t] += v;
    __syncthreads();
  }
  if (t < NA) histmat[t * NBS + b] = a[t] - h;   // exclusive within column
  if (t == 255) btot[b] = a[255];
}

// --- pass 3: scatter pairs into bucket-sorted order (LDS cursors only) -----
__global__ __launch_bounds__(256) void k_scatter(const void* __restrict__ pe,
                                                 const int* __restrict__ histmat,
                                                 const int* __restrict__ btot,
                                                 int2* __restrict__ epairs,
                                                 const int* __restrict__ flags,
                                                 int E, int N, int NB, int CH) {
  __shared__ int sc[NBS];
  __shared__ int cur[NBS];
  int t = threadIdx.x;
  int o0 = (t < NB) ? btot[t] : 0;
  int o1 = (t + 256 < NB) ? btot[t + 256] : 0;
  sc[t] = o0; sc[t + 256] = o1;
  __syncthreads();
  for (int off = 1; off < NBS; off <<= 1) {      // Hillis-Steele, 2 slots/thread
    int v0 = (t >= off) ? sc[t - off] : 0;
    int v1 = (t + 256 >= off) ? sc[t + 256 - off] : 0;
    __syncthreads();
    sc[t] += v0; sc[t + 256] += v1;
    __syncthreads();
  }
  const int* row = histmat + blockIdx.x * NBS;   // contiguous row
  cur[t]       = sc[t] - o0 + row[t];            // bucket base + block cursor
  cur[t + 256] = sc[t + 256] - o1 + row[t + 256];
  __syncthreads();
  int i64 = flags[1];
  int base = blockIdx.x * CH, end = min(base + CH, E);
  for (int e = base + t; e < end; e += 256) {
    int src = clampN(ldi_nt(pe, e, i64), N);
    int dst = clampN(ldi_nt(pe, (long long)E + e, i64), N);
    int pos = atomicAdd(&cur[dst >> 8], 1);      // LDS atomic
    epairs[pos] = make_int2(src, dst);
  }
}

// --- pass 4: per-bucket counting sort -> csr; emits rowp + dinv ------------
__global__ __launch_bounds__(256) void k_bsort(const int2* __restrict__ epairs,
                                               const int* __restrict__ btot,
                                               int* __restrict__ rowp,
                                               float* __restrict__ dinv,
                                               int* __restrict__ csr,
                                               int N, int NB) {
  __shared__ int red[256];
  __shared__ int cnt[256];
  __shared__ int cur2[256];
  __shared__ int s_start;
  int b = blockIdx.x, t = threadIdx.x;
  int acc = 0;
  for (int i = t; i < b; i += 256) acc += btot[i];   // bstart = sum btot[<b]
  red[t] = acc;
  __syncthreads();
  for (int off = 128; off > 0; off >>= 1) {
    if (t < off) red[t] += red[t + off];
    __syncthreads();
  }
  if (t == 0) s_start = red[0];
  __syncthreads();
  int bstart = s_start, bend = bstart + btot[b];
  int node0 = b << 8, nn = min(N - node0, 256);
  cnt[t] = 0;
  __syncthreads();
  for (int j = bstart + t; j < bend; j += 256)
    atomicAdd(&cnt[epairs[j].y - node0], 1);         // LDS atomic
  __syncthreads();
  int c = cnt[t];
  red[t] = c;
  __syncthreads();
  for (int off = 1; off < 256; off <<= 1) {          // inclusive scan
    int v = (t >= off) ? red[t - off] : 0;
    __syncthreads();
    red[t] += v;
    __syncthreads();
  }
  int excl = red[t] - c;
  if (t < nn) {
    rowp[node0 + t] = bstart + excl;
    dinv[node0 + t] = 1.0f / sqrtf((float)(c + 1));  // +1 self loop
    cur2[t] = bstart + excl;
  }
  __syncthreads();
  for (int j = bstart + t; j < bend; j += 256) {
    int2 p = epairs[j];
    int pos = atomicAdd(&cur2[p.y - node0], 1);      // LDS atomic
    csr[pos] = p.x;                                  // ~16KB window: L2-local
  }
  if (b == NB - 1 && t == 0) rowp[N] = bend;
}

// --- gemm1 (MFMA): xw1' = dinv .* (x @ W1), bf16 out -----------------------
__global__ __launch_bounds__(256) void k_gemm1(const void* __restrict__ x,
                                               const unsigned short* __restrict__ w1t,
                                               const float* __restrict__ dinv,
                                               unsigned short* __restrict__ xw1,
                                               const int* __restrict__ flags, int N) {
  int w = threadIdx.x >> 6, lane = threadIdx.x & 63;
  int m = lane & 15, quad = lane >> 4;
  int r0 = blockIdx.x * 64 + w * 16;
  int rr = r0 + m; if (rr >= N) rr = N - 1;
  int f32 = flags[0];
  short8 A[4];
  if (f32) {
    const float* xf = (const float*)x + (size_t)rr * IN_F;
#pragma unroll
    for (int ks = 0; ks < 4; ++ks) {
      const float* p = xf + ks * 32 + quad * 8;
      f32x4 u0 = __builtin_nontemporal_load((const f32x4*)p);
      f32x4 u1 = __builtin_nontemporal_load((const f32x4*)(p + 4));
      short8 a;
#pragma unroll
      for (int j = 0; j < 4; ++j) { a[j] = (short)f2bf(u0[j]); a[4 + j] = (short)f2bf(u1[j]); }
      A[ks] = a;
    }
  } else {
    const unsigned short* xb = (const unsigned short*)x + (size_t)rr * IN_F;
#pragma unroll
    for (int ks = 0; ks < 4; ++ks)
      A[ks] = __builtin_nontemporal_load((const short8*)(xb + ks * 32 + quad * 8));
  }
  float dr[4];
#pragma unroll
  for (int reg = 0; reg < 4; ++reg) {
    int row = r0 + quad * 4 + reg;
    dr[reg] = (row < N) ? dinv[row] : 0.f;
  }
#pragma unroll
  for (int nt = 0; nt < 4; ++nt) {
    f32x4 acc = {0.f, 0.f, 0.f, 0.f};
#pragma unroll
    for (int ks = 0; ks < 4; ++ks) {
      short8 Bf = *(const short8*)(w1t + (nt * 16 + m) * IN_F + ks * 32 + quad * 8);
      acc = __builtin_amdgcn_mfma_f32_16x16x32_bf16(A[ks], Bf, acc, 0, 0, 0);
    }
#pragma unroll
    for (int reg = 0; reg < 4; ++reg) {
      int row = r0 + quad * 4 + reg;
      if (row < N) xw1[(size_t)row * HID_F + nt * 16 + m] = f2bf(dr[reg] * acc[reg]);
    }
  }
}

// --- gather1: h = relu(b1 + dv*(xw1'[v] + sum xw1'[s])), bf16 out ----------
__global__ __launch_bounds__(256) void k_gather1(const int* __restrict__ row_ptr,
                                                 const int* __restrict__ csr_src,
                                                 const float* __restrict__ dinv,
                                                 const unsigned short* __restrict__ xw1,
                                                 const void* __restrict__ b1,
                                                 unsigned short* __restrict__ h,
                                                 const int* __restrict__ flags, int N) {
  int v = blockIdx.x * 4 + (threadIdx.x >> 6);
  if (v >= N) return;
  int lane = threadIdx.x & 63;
  int sub = lane >> 3, l8 = lane & 7;
  int start = row_ptr[v], end = row_ptr[v + 1];
  float a[8] = {0.f,0.f,0.f,0.f,0.f,0.f,0.f,0.f};
  for (int j = start + sub; j < end; j += 8) {
    int s = __builtin_nontemporal_load(csr_src + j);   // sequential stream
    bfx8 wv = *(const bfx8*)(xw1 + (size_t)s * HID_F + l8 * 8);
#pragma unroll
    for (int q = 0; q < 8; ++q) a[q] += bf2f(wv[q]);   // rows pre-scaled
  }
#pragma unroll
  for (int q = 0; q < 8; ++q) {
    a[q] += __shfl_xor(a[q], 8);
    a[q] += __shfl_xor(a[q], 16);
    a[q] += __shfl_xor(a[q], 32);
  }
  if (sub == 0) {
    float dv = dinv[v];
    bfx8 sw = *(const bfx8*)(xw1 + (size_t)v * HID_F + l8 * 8);  // = dv*xw1[v]
    int f32 = flags[0];
    bfx8 r;
#pragma unroll
    for (int q = 0; q < 8; ++q) {
      float val = ldf(b1, l8 * 8 + q, f32) + dv * (bf2f(sw[q]) + a[q]);
      r[q] = f2bf(fmaxf(val, 0.f));
    }
    *(bfx8*)(h + (size_t)v * HID_F + l8 * 8) = r;
  }
}

// --- gemm2 (MFMA): xw2' = dinv .* (h @ W2), bf16 out -----------------------
__global__ __launch_bounds__(256) void k_gemm2(const unsigned short* __restrict__ h,
                                               const unsigned short* __restrict__ w2t,
                                               const float* __restrict__ dinv,
                                               unsigned short* __restrict__ xw2, int N) {
  int w = threadIdx.x >> 6, lane = threadIdx.x & 63;
  int m = lane & 15, quad = lane >> 4;
  int r0 = blockIdx.x * 64 + w * 16;
  int rr = r0 + m; if (rr >= N) rr = N - 1;
  const unsigned short* hb = h + (size_t)rr * HID_F;
  short8 A[2];
#pragma unroll
  for (int ks = 0; ks < 2; ++ks)
    A[ks] = *(const short8*)(hb + ks * 32 + quad * 8);
  float dr[4];
#pragma unroll
  for (int reg = 0; reg < 4; ++reg) {
    int row = r0 + quad * 4 + reg;
    dr[reg] = (row < N) ? dinv[row] : 0.f;
  }
#pragma unroll
  for (int nt = 0; nt < 2; ++nt) {
    f32x4 acc = {0.f, 0.f, 0.f, 0.f};
#pragma unroll
    for (int ks = 0; ks < 2; ++ks) {
      short8 Bf = *(const short8*)(w2t + (nt * 16 + m) * HID_F + ks * 32 + quad * 8);
      acc = __builtin_amdgcn_mfma_f32_16x16x32_bf16(A[ks], Bf, acc, 0, 0, 0);
    }
#pragma unroll
    for (int reg = 0; reg < 4; ++reg) {
      int row = r0 + quad * 4 + reg;
      if (row < N) xw2[(size_t)row * OUT_F + nt * 16 + m] = f2bf(dr[reg] * acc[reg]);
    }
  }
}

// --- gather2: z = b2 + dv*(xw2'[v] + sum xw2'[s]), bf16 out ----------------
__global__ __launch_bounds__(256) void k_gather2(const int* __restrict__ row_ptr,
                                                 const int* __restrict__ csr_src,
                                                 const float* __restrict__ dinv,
                                                 const unsigned short* __restrict__ xw2,
                                                 const void* __restrict__ b2,
                                                 unsigned short* __restrict__ z,
                                                 const int* __restrict__ flags, int N) {
  int v = blockIdx.x * 4 + (threadIdx.x >> 6);
  if (v >= N) return;
  int lane = threadIdx.x & 63;
  int sub = lane >> 3, l8 = lane & 7;
  int start = row_ptr[v], end = row_ptr[v + 1];
  float a[4] = {0.f, 0.f, 0.f, 0.f};
  for (int j = start + sub; j < end; j += 8) {
    int s = __builtin_nontemporal_load(csr_src + j);   // sequential stream
    bfx4 wv = *(const bfx4*)(xw2 + (size_t)s * OUT_F + l8 * 4);
#pragma unroll
    for (int q = 0; q < 4; ++q) a[q] += bf2f(wv[q]);   // rows pre-scaled
  }
#pragma unroll
  for (int q = 0; q < 4; ++q) {
    a[q] += __shfl_xor(a[q], 8);
    a[q] += __shfl_xor(a[q], 16);
    a[q] += __shfl_xor(a[q], 32);
  }
  if (sub == 0) {
    float dv = dinv[v];
    bfx4 sw = *(const bfx4*)(xw2 + (size_t)v * OUT_F + l8 * 4);  // = dv*xw2[v]
    int f32 = flags[0];
    bfx4 r;
#pragma unroll
    for (int q = 0; q < 4; ++q)
      r[q] = f2bf(ldf(b2, l8 * 4 + q, f32) + dv * (bf2f(sw[q]) + a[q]));
    *(bfx4*)(z + (size_t)v * OUT_F + l8 * 4) = r;
  }
}

// --- decode: 4 lanes/edge x DEC_U edges/quad, phase-batched loads ----------
__global__ __launch_bounds__(256) void k_decode(const void* __restrict__ pe,
                                                const void* __restrict__ ne,
                                                const unsigned short* __restrict__ z,
                                                float* __restrict__ out,
                                                const int* __restrict__ flags,
                                                int E, int N, int Q) {
  int q = blockIdx.x * 64 + (threadIdx.x >> 2);  // global quad id
  int g = threadIdx.x & 3;
  int twoE = 2 * E;
  int i64 = flags[1];
  int ee[DEC_U], src[DEC_U], dst[DEC_U];
  bool ok[DEC_U];
#pragma unroll
  for (int u = 0; u < DEC_U; ++u) {              // phase 1: index loads
    int e = q + u * Q;
    ee[u] = e; ok[u] = (e < twoE);
    src[u] = 0; dst[u] = 0;
    if (ok[u]) {
      if (e < E) { src[u] = ldi_nt(pe, e, i64); dst[u] = ldi_nt(pe, (long long)E + e, i64); }
      else       { src[u] = ldi_nt(ne, e - E, i64); dst[u] = ldi_nt(ne, e, i64); }
    }
  }
  bfx8 av[DEC_U], bv[DEC_U];
#pragma unroll
  for (int u = 0; u < DEC_U; ++u) {              // phase 2: z-row loads
    int cs = clampN(src[u], N), cd = clampN(dst[u], N);
    av[u] = *(const bfx8*)(z + (size_t)cs * OUT_F + g * 8);
    bv[u] = *(const bfx8*)(z + (size_t)cd * OUT_F + g * 8);
  }
#pragma unroll
  for (int u = 0; u < DEC_U; ++u) {              // phase 3: compute + store
    if (!ok[u]) continue;
    int e = ee[u];
    if (g == 1) __builtin_nontemporal_store((float)src[u], out + twoE + e);
    if (g == 2) __builtin_nontemporal_store((float)dst[u], out + 2 * twoE + e);
    float s = 0.f;
#pragma unroll
    for (int k = 0; k < 8; ++k) s += bf2f(av[u][k]) * bf2f(bv[u][k]);
    s += __shfl_xor(s, 1);
    s += __shfl_xor(s, 2);
    s = fminf(fmaxf(s, -500.0f), 500.0f);        // insurance rail (R2 notes)
    if (g == 0) __builtin_nontemporal_store(s, out + e);
  }
}

extern "C" void kernel_launch(void* const* d_in, const int* in_sizes, int n_in,
                              void* d_out, int out_size, void* d_ws, size_t ws_size,
                              hipStream_t stream) {
  const void* x  = d_in[0];
  const void* W1 = d_in[1];
  const void* b1 = d_in[2];
  const void* W2 = d_in[3];
  const void* b2 = d_in[4];
  const void* pe = d_in[5];
  const void* ne = d_in[6];
  int N = in_sizes[0] / IN_F;       // 100000
  int E = in_sizes[5] / 2;          // 1600000
  int NB = (N + 255) >> 8;          // 391 buckets
  int CH = (E + NA - 1) / NA;       // 8000 edges/chunk

  int*   ip    = (int*)d_ws;
  float* ws    = (float*)d_ws;
  int*   flags = ip + OFF_FLAGS;
  unsigned short* w1t = (unsigned short*)(ip + OFF_W1T);
  unsigned short* w2t = (unsigned short*)(ip + OFF_W2T);
  int*   hist  = ip + OFF_HIST;
  int*   btot  = ip + OFF_BTOT;
  int*   rowp  = ip + OFF_ROWP;
  float* dinv  = ws + OFF_DINV;
  int2*  epairs= (int2*)(ip + OFF_EPAIRS);
  int*   csr   = ip + OFF_CSR;
  unsigned short* xw1 = (unsigned short*)(ip + OFF_XW1);
  unsigned short* h   = (unsigned short*)(ip + OFF_H);
  unsigned short* xw2 = (unsigned short*)(ip + OFF_XW2);
  unsigned short* zz  = (unsigned short*)(ip + OFF_Z);
  float* out   = (float*)d_out;

  k_prep<<<1, 256, 0, stream>>>(x, pe, W1, W2, flags, w1t, w2t);
  k_hist<<<NA, 256, 0, stream>>>(pe, hist, flags, E, N, CH);
  k_colscan<<<NB, 256, 0, stream>>>(hist, btot);
  k_scatter<<<NA, 256, 0, stream>>>(pe, hist, btot, epairs, flags, E, N, NB, CH);
  k_bsort<<<NB, 256, 0, stream>>>(epairs, btot, rowp, dinv, csr, N, NB);
  k_gemm1<<<(N + 63) / 64, 256, 0, stream>>>(x, w1t, dinv, xw1, flags, N);
  k_gather1<<<(N + 3) / 4, 256, 0, stream>>>(rowp, csr, dinv, xw1, b1, h, flags, N);
  k_gemm2<<<(N + 63) / 64, 256, 0, stream>>>(h, w2t, dinv, xw2, N);
  k_gather2<<<(N + 3) / 4, 256, 0, stream>>>(rowp, csr, dinv, xw2, b2, zz, flags, N);
  int edges_per_block = 64 * DEC_U;                       // 256
  int DB = (2 * E + edges_per_block - 1) / edges_per_block;  // 12500
  k_decode<<<DB, 256, 0, stream>>>(pe, ne, zz, out, flags, E, N, DB * 64);
}

// Round 7
// 378.175 us; speedup vs baseline: 1.4772x; 1.0107x over previous
//
#include <hip/hip_runtime.h>
#include <hip/hip_bf16.h>

// ---------------------------------------------------------------------------
// GCN link predictor, R15: R14 + CSR-build parallelism fix (NA 200->512).
// R14 post-mortem: decode (60us) and gather1 (~55) sit at the ~130-150G
// line-requests/s floor; gather2/gemms/prep ~50 combined. The remaining
// ~215us is the CSR build: NA=200 blocks = 0.78 blocks/CU = 1 wave/SIMD on
// hist/scatter -- ~900cyc HBM latency fully exposed, ~31 loop trips. Fix:
// NA=512 (2 blocks/CU, 12 trips). histmat (512x512 ints = 1MB) RELOCATED to
// the h region (h written only after CSR build; stream-ordered reuse, zero
// ws growth). colscan rewritten 512-wide (two-slot Hillis-Steele).
//   h = relu(b1 + dv*(xw1'[v] + sum_s xw1'[s])),  xw1' = dinv.*(x @ W1)
//   z = b2 + dv*(xw2'[v] + sum_s xw2'[s]),        xw2' = dinv.*(h @ W2)
//   logits[e] = dot(z[src], z[dst]) over [pos; neg]
// Output: FLOAT32 [logits(2E)][edge row0(2E)][row1(2E)] (established R2).
// ---------------------------------------------------------------------------

#define IN_F  128
#define HID_F 64
#define OUT_F 32
#define NA    512      // edge-chunk blocks for hist/scatter (2 blocks/CU)
#define NBS   512      // histogram stride (>= NB=391 buckets of 256 nodes)
#define DEC_U 4        // edges per lane-quad in decode

// workspace element offsets (4-byte units); all table bases 128B-aligned.
// N=100000, E=1600000; end = 14,708,096 ints = 58.83 MB (unchanged).
// NOTE: histmat (NA*NBS = 262144 ints) now ALIASES the h region -- h is
// first written by k_gather1, strictly after k_scatter/k_bsort complete.
#define OFF_FLAGS   0          // 2 ints
#define OFF_W1T     32         // 8192 bf16 = 4096 ints
#define OFF_W2T     4128       // 2048 bf16 = 1024 ints
#define OFF_BTOT    107552     // 512 ints
#define OFF_ROWP    108064     // N+1 ints (-> 208065)
#define OFF_DINV    208096     // N floats
#define OFF_EPAIRS  308096     // 2E ints (int2 pairs; byte%8==0)
#define OFF_CSR     3508096    // E ints
#define OFF_XW1     5108096    // N*64 bf16 = 3.2M ints (base byte%128==0)
#define OFF_H       8308096    // N*64 bf16; ALSO histmat during CSR build
#define OFF_XW2     11508096   // N*32 bf16 = 1.6M ints
#define OFF_Z       13108096   // N*32 bf16 -> end 14708096

typedef short short8 __attribute__((ext_vector_type(8)));
typedef float f32x4  __attribute__((ext_vector_type(4)));
typedef unsigned short bfx8 __attribute__((ext_vector_type(8)));
typedef unsigned short bfx4 __attribute__((ext_vector_type(4)));

__device__ __forceinline__ float ldf(const void* p, int i, int f32) {
  if (f32) return ((const float*)p)[i];
  unsigned int w = ((unsigned int)((const unsigned short*)p)[i]) << 16;
  return __uint_as_float(w);
}
__device__ __forceinline__ int ldi(const void* p, long long i, int i64) {
  if (i64) return (int)((const long long*)p)[i];
  return ((const int*)p)[i];
}
// non-temporal index load: single-use streams, keep out of L2
__device__ __forceinline__ int ldi_nt(const void* p, long long i, int i64) {
  if (i64) return (int)__builtin_nontemporal_load(((const long long*)p) + i);
  return __builtin_nontemporal_load(((const int*)p) + i);
}
__device__ __forceinline__ int clampN(int v, int N) {
  unsigned u = (unsigned)v;
  return (u < (unsigned)N) ? v : 0;
}
__device__ __forceinline__ unsigned short f2bf(float f) {   // RNE f32->bf16
  unsigned u = __float_as_uint(f);
  return (unsigned short)((u + 0x7FFFu + ((u >> 16) & 1u)) >> 16);
}
__device__ __forceinline__ float bf2f(unsigned short h) {
  return __uint_as_float(((unsigned)h) << 16);
}

// --- prep (grid 1): detect dtypes + transpose weights ----------------------
__global__ __launch_bounds__(256) void k_prep(const void* __restrict__ x,
                                              const void* __restrict__ pe,
                                              const void* __restrict__ W1,
                                              const void* __restrict__ W2,
                                              int* __restrict__ flags,
                                              unsigned short* __restrict__ w1t,
                                              unsigned short* __restrict__ w2t) {
  __shared__ int s_big, s_nzodd;
  int t = threadIdx.x;
  if (t == 0) { s_big = 0; s_nzodd = 0; }
  __syncthreads();
  int nbig = 0, nz = 0;
  const unsigned short* xb = (const unsigned short*)x;
  for (int i = t; i < 4096; i += 256) {
    int ex = (xb[i] >> 7) & 0xFF;
    if (ex >= 147) nbig++;               // |v|>=2^20 impossible for N(0,1) bf16
  }
  const int* pi = (const int*)pe;
  for (int i = t; i < 2048; i += 256) {
    if (pi[2 * i + 1] != 0) nz++;        // int64 hi-words all zero
  }
  atomicAdd(&s_big, nbig);
  atomicAdd(&s_nzodd, nz);
  __syncthreads();
  int f32 = (s_big > 400) ? 1 : 0;
  if (t == 0) {
    flags[0] = f32;
    flags[1] = (s_nzodd < 100) ? 1 : 0;
  }
  for (int i = t; i < HID_F * IN_F; i += 256) {   // W1T[n*128+k] = W1[k*64+n]
    int n = i >> 7, k = i & 127;
    w1t[i] = f2bf(ldf(W1, k * HID_F + n, f32));
  }
  for (int i = t; i < OUT_F * HID_F; i += 256) {  // W2T[n*64+k] = W2[k*32+n]
    int n = i >> 6, k = i & 63;
    w2t[i] = f2bf(ldf(W2, k * OUT_F + n, f32));
  }
}

// --- CSR build pass 1: per-chunk LDS histogram over buckets ---------------
__global__ __launch_bounds__(256) void k_hist(const void* __restrict__ pe,
                                              int* __restrict__ histmat,
                                              const int* __restrict__ flags,
                                              int E, int N, int CH) {
  __shared__ int hist[NBS];
  int t = threadIdx.x;
  for (int i = t; i < NBS; i += 256) hist[i] = 0;
  __syncthreads();
  int i64 = flags[1];
  int base = blockIdx.x * CH, end = min(base + CH, E);
  for (int e = base + t; e < end; e += 256) {
    int dst = clampN(ldi_nt(pe, (long long)E + e, i64), N);
    atomicAdd(&hist[dst >> 8], 1);       // LDS atomic
  }
  __syncthreads();
  for (int i = t; i < NBS; i += 256) histmat[blockIdx.x * NBS + i] = hist[i];
}

// --- pass 2: per-bucket column exclusive scan over NA=512 chunk rows -------
__global__ __launch_bounds__(256) void k_colscan(int* __restrict__ histmat,
                                                 int* __restrict__ btot) {
  __shared__ int a[NA];                  // 512, two slots per thread
  int b = blockIdx.x, t = threadIdx.x;
  int h0 = histmat[t * NBS + b];
  int h1 = histmat[(t + 256) * NBS + b];
  a[t] = h0; a[t + 256] = h1;
  __syncthreads();
  for (int off = 1; off < NA; off <<= 1) {
    int v0 = (t >= off) ? a[t - off] : 0;
    int v1 = (t + 256 >= off) ? a[t + 256 - off] : 0;
    __syncthreads();
    a[t] += v0; a[t + 256] += v1;
    __syncthreads();
  }
  histmat[t * NBS + b] = a[t] - h0;             // exclusive within column
  histmat[(t + 256) * NBS + b] = a[t + 256] - h1;
  if (t == 255) btot[b] = a[NA - 1];
}

// --- pass 3: scatter pairs into bucket-sorted order (LDS cursors only) -----
__global__ __launch_bounds__(256) void k_scatter(const void* __restrict__ pe,
                                                 const int* __restrict__ histmat,
                                                 const int* __restrict__ btot,
                                                 int2* __restrict__ epairs,
                                                 const int* __restrict__ flags,
                                                 int E, int N, int NB, int CH) {
  __shared__ int sc[NBS];
  __shared__ int cur[NBS];
  int t = threadIdx.x;
  int o0 = (t < NB) ? btot[t] : 0;
  int o1 = (t + 256 < NB) ? btot[t + 256] : 0;
  sc[t] = o0; sc[t + 256] = o1;
  __syncthreads();
  for (int off = 1; off < NBS; off <<= 1) {      // Hillis-Steele, 2 slots/thread
    int v0 = (t >= off) ? sc[t - off] : 0;
    int v1 = (t + 256 >= off) ? sc[t + 256 - off] : 0;
    __syncthreads();
    sc[t] += v0; sc[t + 256] += v1;
    __syncthreads();
  }
  const int* row = histmat + blockIdx.x * NBS;   // contiguous row
  cur[t]       = sc[t] - o0 + row[t];            // bucket base + block cursor
  cur[t + 256] = sc[t + 256] - o1 + row[t + 256];
  __syncthreads();
  int i64 = flags[1];
  int base = blockIdx.x * CH, end = min(base + CH, E);
  for (int e = base + t; e < end; e += 256) {
    int src = clampN(ldi_nt(pe, e, i64), N);
    int dst = clampN(ldi_nt(pe, (long long)E + e, i64), N);
    int pos = atomicAdd(&cur[dst >> 8], 1);      // LDS atomic
    epairs[pos] = make_int2(src, dst);
  }
}

// --- pass 4: per-bucket counting sort -> csr; emits rowp + dinv ------------
__global__ __launch_bounds__(256) void k_bsort(const int2* __restrict__ epairs,
                                               const int* __restrict__ btot,
                                               int* __restrict__ rowp,
                                               float* __restrict__ dinv,
                                               int* __restrict__ csr,
                                               int N, int NB) {
  __shared__ int red[256];
  __shared__ int cnt[256];
  __shared__ int cur2[256];
  __shared__ int s_start;
  int b = blockIdx.x, t = threadIdx.x;
  int acc = 0;
  for (int i = t; i < b; i += 256) acc += btot[i];   // bstart = sum btot[<b]
  red[t] = acc;
  __syncthreads();
  for (int off = 128; off > 0; off >>= 1) {
    if (t < off) red[t] += red[t + off];
    __syncthreads();
  }
  if (t == 0) s_start = red[0];
  __syncthreads();
  int bstart = s_start, bend = bstart + btot[b];
  int node0 = b << 8, nn = min(N - node0, 256);
  cnt[t] = 0;
  __syncthreads();
  for (int j = bstart + t; j < bend; j += 256)
    atomicAdd(&cnt[epairs[j].y - node0], 1);         // LDS atomic
  __syncthreads();
  int c = cnt[t];
  red[t] = c;
  __syncthreads();
  for (int off = 1; off < 256; off <<= 1) {          // inclusive scan
    int v = (t >= off) ? red[t - off] : 0;
    __syncthreads();
    red[t] += v;
    __syncthreads();
  }
  int excl = red[t] - c;
  if (t < nn) {
    rowp[node0 + t] = bstart + excl;
    dinv[node0 + t] = 1.0f / sqrtf((float)(c + 1));  // +1 self loop
    cur2[t] = bstart + excl;
  }
  __syncthreads();
  for (int j = bstart + t; j < bend; j += 256) {
    int2 p = epairs[j];
    int pos = atomicAdd(&cur2[p.y - node0], 1);      // LDS atomic
    csr[pos] = p.x;                                  // ~16KB window: L2-local
  }
  if (b == NB - 1 && t == 0) rowp[N] = bend;
}

// --- gemm1 (MFMA): xw1' = dinv .* (x @ W1), bf16 out -----------------------
__global__ __launch_bounds__(256) void k_gemm1(const void* __restrict__ x,
                                               const unsigned short* __restrict__ w1t,
                                               const float* __restrict__ dinv,
                                               unsigned short* __restrict__ xw1,
                                               const int* __restrict__ flags, int N) {
  int w = threadIdx.x >> 6, lane = threadIdx.x & 63;
  int m = lane & 15, quad = lane >> 4;
  int r0 = blockIdx.x * 64 + w * 16;
  int rr = r0 + m; if (rr >= N) rr = N - 1;
  int f32 = flags[0];
  short8 A[4];
  if (f32) {
    const float* xf = (const float*)x + (size_t)rr * IN_F;
#pragma unroll
    for (int ks = 0; ks < 4; ++ks) {
      const float* p = xf + ks * 32 + quad * 8;
      f32x4 u0 = __builtin_nontemporal_load((const f32x4*)p);
      f32x4 u1 = __builtin_nontemporal_load((const f32x4*)(p + 4));
      short8 a;
#pragma unroll
      for (int j = 0; j < 4; ++j) { a[j] = (short)f2bf(u0[j]); a[4 + j] = (short)f2bf(u1[j]); }
      A[ks] = a;
    }
  } else {
    const unsigned short* xb = (const unsigned short*)x + (size_t)rr * IN_F;
#pragma unroll
    for (int ks = 0; ks < 4; ++ks)
      A[ks] = __builtin_nontemporal_load((const short8*)(xb + ks * 32 + quad * 8));
  }
  float dr[4];
#pragma unroll
  for (int reg = 0; reg < 4; ++reg) {
    int row = r0 + quad * 4 + reg;
    dr[reg] = (row < N) ? dinv[row] : 0.f;
  }
#pragma unroll
  for (int nt = 0; nt < 4; ++nt) {
    f32x4 acc = {0.f, 0.f, 0.f, 0.f};
#pragma unroll
    for (int ks = 0; ks < 4; ++ks) {
      short8 Bf = *(const short8*)(w1t + (nt * 16 + m) * IN_F + ks * 32 + quad * 8);
      acc = __builtin_amdgcn_mfma_f32_16x16x32_bf16(A[ks], Bf, acc, 0, 0, 0);
    }
#pragma unroll
    for (int reg = 0; reg < 4; ++reg) {
      int row = r0 + quad * 4 + reg;
      if (row < N) xw1[(size_t)row * HID_F + nt * 16 + m] = f2bf(dr[reg] * acc[reg]);
    }
  }
}

// --- gather1: h = relu(b1 + dv*(xw1'[v] + sum xw1'[s])), bf16 out ----------
__global__ __launch_bounds__(256) void k_gather1(const int* __restrict__ row_ptr,
                                                 const int* __restrict__ csr_src,
                                                 const float* __restrict__ dinv,
                                                 const unsigned short* __restrict__ xw1,
                                                 const void* __restrict__ b1,
                                                 unsigned short* __restrict__ h,
                                                 const int* __restrict__ flags, int N) {
  int v = blockIdx.x * 4 + (threadIdx.x >> 6);
  if (v >= N) return;
  int lane = threadIdx.x & 63;
  int sub = lane >> 3, l8 = lane & 7;
  int start = row_ptr[v], end = row_ptr[v + 1];
  float a[8] = {0.f,0.f,0.f,0.f,0.f,0.f,0.f,0.f};
  for (int j = start + sub; j < end; j += 8) {
    int s = __builtin_nontemporal_load(csr_src + j);   // sequential stream
    bfx8 wv = *(const bfx8*)(xw1 + (size_t)s * HID_F + l8 * 8);
#pragma unroll
    for (int q = 0; q < 8; ++q) a[q] += bf2f(wv[q]);   // rows pre-scaled
  }
#pragma unroll
  for (int q = 0; q < 8; ++q) {
    a[q] += __shfl_xor(a[q], 8);
    a[q] += __shfl_xor(a[q], 16);
    a[q] += __shfl_xor(a[q], 32);
  }
  if (sub == 0) {
    float dv = dinv[v];
    bfx8 sw = *(const bfx8*)(xw1 + (size_t)v * HID_F + l8 * 8);  // = dv*xw1[v]
    int f32 = flags[0];
    bfx8 r;
#pragma unroll
    for (int q = 0; q < 8; ++q) {
      float val = ldf(b1, l8 * 8 + q, f32) + dv * (bf2f(sw[q]) + a[q]);
      r[q] = f2bf(fmaxf(val, 0.f));
    }
    *(bfx8*)(h + (size_t)v * HID_F + l8 * 8) = r;
  }
}

// --- gemm2 (MFMA): xw2' = dinv .* (h @ W2), bf16 out -----------------------
__global__ __launch_bounds__(256) void k_gemm2(const unsigned short* __restrict__ h,
                                               const unsigned short* __restrict__ w2t,
                                               const float* __restrict__ dinv,
                                               unsigned short* __restrict__ xw2, int N) {
  int w = threadIdx.x >> 6, lane = threadIdx.x & 63;
  int m = lane & 15, quad = lane >> 4;
  int r0 = blockIdx.x * 64 + w * 16;
  int rr = r0 + m; if (rr >= N) rr = N - 1;
  const unsigned short* hb = h + (size_t)rr * HID_F;
  short8 A[2];
#pragma unroll
  for (int ks = 0; ks < 2; ++ks)
    A[ks] = *(const short8*)(hb + ks * 32 + quad * 8);
  float dr[4];
#pragma unroll
  for (int reg = 0; reg < 4; ++reg) {
    int row = r0 + quad * 4 + reg;
    dr[reg] = (row < N) ? dinv[row] : 0.f;
  }
#pragma unroll
  for (int nt = 0; nt < 2; ++nt) {
    f32x4 acc = {0.f, 0.f, 0.f, 0.f};
#pragma unroll
    for (int ks = 0; ks < 2; ++ks) {
      short8 Bf = *(const short8*)(w2t + (nt * 16 + m) * HID_F + ks * 32 + quad * 8);
      acc = __builtin_amdgcn_mfma_f32_16x16x32_bf16(A[ks], Bf, acc, 0, 0, 0);
    }
#pragma unroll
    for (int reg = 0; reg < 4; ++reg) {
      int row = r0 + quad * 4 + reg;
      if (row < N) xw2[(size_t)row * OUT_F + nt * 16 + m] = f2bf(dr[reg] * acc[reg]);
    }
  }
}

// --- gather2: z = b2 + dv*(xw2'[v] + sum xw2'[s]), bf16 out ----------------
__global__ __launch_bounds__(256) void k_gather2(const int* __restrict__ row_ptr,
                                                 const int* __restrict__ csr_src,
                                                 const float* __restrict__ dinv,
                                                 const unsigned short* __restrict__ xw2,
                                                 const void* __restrict__ b2,
                                                 unsigned short* __restrict__ z,
                                                 const int* __restrict__ flags, int N) {
  int v = blockIdx.x * 4 + (threadIdx.x >> 6);
  if (v >= N) return;
  int lane = threadIdx.x & 63;
  int sub = lane >> 3, l8 = lane & 7;
  int start = row_ptr[v], end = row_ptr[v + 1];
  float a[4] = {0.f, 0.f, 0.f, 0.f};
  for (int j = start + sub; j < end; j += 8) {
    int s = __builtin_nontemporal_load(csr_src + j);   // sequential stream
    bfx4 wv = *(const bfx4*)(xw2 + (size_t)s * OUT_F + l8 * 4);
#pragma unroll
    for (int q = 0; q < 4; ++q) a[q] += bf2f(wv[q]);   // rows pre-scaled
  }
#pragma unroll
  for (int q = 0; q < 4; ++q) {
    a[q] += __shfl_xor(a[q], 8);
    a[q] += __shfl_xor(a[q], 16);
    a[q] += __shfl_xor(a[q], 32);
  }
  if (sub == 0) {
    float dv = dinv[v];
    bfx4 sw = *(const bfx4*)(xw2 + (size_t)v * OUT_F + l8 * 4);  // = dv*xw2[v]
    int f32 = flags[0];
    bfx4 r;
#pragma unroll
    for (int q = 0; q < 4; ++q)
      r[q] = f2bf(ldf(b2, l8 * 4 + q, f32) + dv * (bf2f(sw[q]) + a[q]));
    *(bfx4*)(z + (size_t)v * OUT_F + l8 * 4) = r;
  }
}

// --- decode: 4 lanes/edge x DEC_U edges/quad, phase-batched loads ----------
__global__ __launch_bounds__(256) void k_decode(const void* __restrict__ pe,
                                                const void* __restrict__ ne,
                                                const unsigned short* __restrict__ z,
                                                float* __restrict__ out,
                                                const int* __restrict__ flags,
                                                int E, int N, int Q) {
  int q = blockIdx.x * 64 + (threadIdx.x >> 2);  // global quad id
  int g = threadIdx.x & 3;
  int twoE = 2 * E;
  int i64 = flags[1];
  int ee[DEC_U], src[DEC_U], dst[DEC_U];
  bool ok[DEC_U];
#pragma unroll
  for (int u = 0; u < DEC_U; ++u) {              // phase 1: index loads
    int e = q + u * Q;
    ee[u] = e; ok[u] = (e < twoE);
    src[u] = 0; dst[u] = 0;
    if (ok[u]) {
      if (e < E) { src[u] = ldi_nt(pe, e, i64); dst[u] = ldi_nt(pe, (long long)E + e, i64); }
      else       { src[u] = ldi_nt(ne, e - E, i64); dst[u] = ldi_nt(ne, e, i64); }
    }
  }
  bfx8 av[DEC_U], bv[DEC_U];
#pragma unroll
  for (int u = 0; u < DEC_U; ++u) {              // phase 2: z-row loads
    int cs = clampN(src[u], N), cd = clampN(dst[u], N);
    av[u] = *(const bfx8*)(z + (size_t)cs * OUT_F + g * 8);
    bv[u] = *(const bfx8*)(z + (size_t)cd * OUT_F + g * 8);
  }
#pragma unroll
  for (int u = 0; u < DEC_U; ++u) {              // phase 3: compute + store
    if (!ok[u]) continue;
    int e = ee[u];
    if (g == 1) __builtin_nontemporal_store((float)src[u], out + twoE + e);
    if (g == 2) __builtin_nontemporal_store((float)dst[u], out + 2 * twoE + e);
    float s = 0.f;
#pragma unroll
    for (int k = 0; k < 8; ++k) s += bf2f(av[u][k]) * bf2f(bv[u][k]);
    s += __shfl_xor(s, 1);
    s += __shfl_xor(s, 2);
    s = fminf(fmaxf(s, -500.0f), 500.0f);        // insurance rail (R2 notes)
    if (g == 0) __builtin_nontemporal_store(s, out + e);
  }
}

extern "C" void kernel_launch(void* const* d_in, const int* in_sizes, int n_in,
                              void* d_out, int out_size, void* d_ws, size_t ws_size,
                              hipStream_t stream) {
  const void* x  = d_in[0];
  const void* W1 = d_in[1];
  const void* b1 = d_in[2];
  const void* W2 = d_in[3];
  const void* b2 = d_in[4];
  const void* pe = d_in[5];
  const void* ne = d_in[6];
  int N = in_sizes[0] / IN_F;       // 100000
  int E = in_sizes[5] / 2;          // 1600000
  int NB = (N + 255) >> 8;          // 391 buckets
  int CH = (E + NA - 1) / NA;       // 3125 edges/chunk

  int*   ip    = (int*)d_ws;
  float* ws    = (float*)d_ws;
  int*   flags = ip + OFF_FLAGS;
  unsigned short* w1t = (unsigned short*)(ip + OFF_W1T);
  unsigned short* w2t = (unsigned short*)(ip + OFF_W2T);
  int*   hist  = ip + OFF_H;        // histmat aliases h region (pre-gather1)
  int*   btot  = ip + OFF_BTOT;
  int*   rowp  = ip + OFF_ROWP;
  float* dinv  = ws + OFF_DINV;
  int2*  epairs= (int2*)(ip + OFF_EPAIRS);
  int*   csr   = ip + OFF_CSR;
  unsigned short* xw1 = (unsigned short*)(ip + OFF_XW1);
  unsigned short* h   = (unsigned short*)(ip + OFF_H);
  unsigned short* xw2 = (unsigned short*)(ip + OFF_XW2);
  unsigned short* zz  = (unsigned short*)(ip + OFF_Z);
  float* out   = (float*)d_out;

  k_prep<<<1, 256, 0, stream>>>(x, pe, W1, W2, flags, w1t, w2t);
  k_hist<<<NA, 256, 0, stream>>>(pe, hist, flags, E, N, CH);
  k_colscan<<<NB, 256, 0, stream>>>(hist, btot);
  k_scatter<<<NA, 256, 0, stream>>>(pe, hist, btot, epairs, flags, E, N, NB, CH);
  k_bsort<<<NB, 256, 0, stream>>>(epairs, btot, rowp, dinv, csr, N, NB);
  k_gemm1<<<(N + 63) / 64, 256, 0, stream>>>(x, w1t, dinv, xw1, flags, N);
  k_gather1<<<(N + 3) / 4, 256, 0, stream>>>(rowp, csr, dinv, xw1, b1, h, flags, N);
  k_gemm2<<<(N + 63) / 64, 256, 0, stream>>>(h, w2t, dinv, xw2, N);
  k_gather2<<<(N + 3) / 4, 256, 0, stream>>>(rowp, csr, dinv, xw2, b2, zz, flags, N);
  int edges_per_block = 64 * DEC_U;                       // 256
  int DB = (2 * E + edges_per_block - 1) / edges_per_block;  // 12500
  k_decode<<<DB, 256, 0, stream>>>(pe, ne, zz, out, flags, E, N, DB * 64);
}

// Round 8
// 371.471 us; speedup vs baseline: 1.5039x; 1.0180x over previous
//
#include <hip/hip_runtime.h>
#include <hip/hip_bf16.h>

// ---------------------------------------------------------------------------
// GCN link predictor, R16: R15 + gather 2-ahead ILP batching + decode split.
// R15 post-mortem: CSR-build occupancy was NOT the sink (-4us). gather1 at
// 65G lines/s is 2x below the ~130G device line rate decode shows -- its
// rowp->csr->row chain exposes latency (17 lines in flight/wave, loop not
// compiler-pipelineable). Fix: batch 2 neighbor slots per iteration (csr[j],
// csr[j+8] issued together, then both rows; add order preserved -> bit-
// identical). Decode split into pos/neg half-range dispatches (~30us each):
// neutral on time, makes next round's top-5 reveal the sub-60us kernels.
//   h = relu(b1 + dv*(xw1'[v] + sum_s xw1'[s])),  xw1' = dinv.*(x @ W1)
//   z = b2 + dv*(xw2'[v] + sum_s xw2'[s]),        xw2' = dinv.*(h @ W2)
//   logits[e] = dot(z[src], z[dst]) over [pos; neg]
// Output: FLOAT32 [logits(2E)][edge row0(2E)][row1(2E)] (established R2).
// ---------------------------------------------------------------------------

#define IN_F  128
#define HID_F 64
#define OUT_F 32
#define NA    512      // edge-chunk blocks for hist/scatter (2 blocks/CU)
#define NBS   512      // histogram stride (>= NB=391 buckets of 256 nodes)
#define DEC_U 4        // edges per lane-quad in decode

// workspace element offsets (4-byte units); all table bases 128B-aligned.
// N=100000, E=1600000; end = 14,708,096 ints = 58.83 MB (unchanged).
// histmat (NA*NBS = 262144 ints) ALIASES the h region (h written only by
// k_gather1, strictly after k_scatter/k_bsort complete).
#define OFF_FLAGS   0          // 2 ints
#define OFF_W1T     32         // 8192 bf16 = 4096 ints
#define OFF_W2T     4128       // 2048 bf16 = 1024 ints
#define OFF_BTOT    107552     // 512 ints
#define OFF_ROWP    108064     // N+1 ints (-> 208065)
#define OFF_DINV    208096     // N floats
#define OFF_EPAIRS  308096     // 2E ints (int2 pairs; byte%8==0)
#define OFF_CSR     3508096    // E ints
#define OFF_XW1     5108096    // N*64 bf16 = 3.2M ints (base byte%128==0)
#define OFF_H       8308096    // N*64 bf16; ALSO histmat during CSR build
#define OFF_XW2     11508096   // N*32 bf16 = 1.6M ints
#define OFF_Z       13108096   // N*32 bf16 -> end 14708096

typedef short short8 __attribute__((ext_vector_type(8)));
typedef float f32x4  __attribute__((ext_vector_type(4)));
typedef unsigned short bfx8 __attribute__((ext_vector_type(8)));
typedef unsigned short bfx4 __attribute__((ext_vector_type(4)));

__device__ __forceinline__ float ldf(const void* p, int i, int f32) {
  if (f32) return ((const float*)p)[i];
  unsigned int w = ((unsigned int)((const unsigned short*)p)[i]) << 16;
  return __uint_as_float(w);
}
__device__ __forceinline__ int ldi(const void* p, long long i, int i64) {
  if (i64) return (int)((const long long*)p)[i];
  return ((const int*)p)[i];
}
// non-temporal index load: single-use streams, keep out of L2
__device__ __forceinline__ int ldi_nt(const void* p, long long i, int i64) {
  if (i64) return (int)__builtin_nontemporal_load(((const long long*)p) + i);
  return __builtin_nontemporal_load(((const int*)p) + i);
}
__device__ __forceinline__ int clampN(int v, int N) {
  unsigned u = (unsigned)v;
  return (u < (unsigned)N) ? v : 0;
}
__device__ __forceinline__ unsigned short f2bf(float f) {   // RNE f32->bf16
  unsigned u = __float_as_uint(f);
  return (unsigned short)((u + 0x7FFFu + ((u >> 16) & 1u)) >> 16);
}
__device__ __forceinline__ float bf2f(unsigned short h) {
  return __uint_as_float(((unsigned)h) << 16);
}

// --- prep (grid 1): detect dtypes + transpose weights ----------------------
__global__ __launch_bounds__(256) void k_prep(const void* __restrict__ x,
                                              const void* __restrict__ pe,
                                              const void* __restrict__ W1,
                                              const void* __restrict__ W2,
                                              int* __restrict__ flags,
                                              unsigned short* __restrict__ w1t,
                                              unsigned short* __restrict__ w2t) {
  __shared__ int s_big, s_nzodd;
  int t = threadIdx.x;
  if (t == 0) { s_big = 0; s_nzodd = 0; }
  __syncthreads();
  int nbig = 0, nz = 0;
  const unsigned short* xb = (const unsigned short*)x;
  for (int i = t; i < 4096; i += 256) {
    int ex = (xb[i] >> 7) & 0xFF;
    if (ex >= 147) nbig++;               // |v|>=2^20 impossible for N(0,1) bf16
  }
  const int* pi = (const int*)pe;
  for (int i = t; i < 2048; i += 256) {
    if (pi[2 * i + 1] != 0) nz++;        // int64 hi-words all zero
  }
  atomicAdd(&s_big, nbig);
  atomicAdd(&s_nzodd, nz);
  __syncthreads();
  int f32 = (s_big > 400) ? 1 : 0;
  if (t == 0) {
    flags[0] = f32;
    flags[1] = (s_nzodd < 100) ? 1 : 0;
  }
  for (int i = t; i < HID_F * IN_F; i += 256) {   // W1T[n*128+k] = W1[k*64+n]
    int n = i >> 7, k = i & 127;
    w1t[i] = f2bf(ldf(W1, k * HID_F + n, f32));
  }
  for (int i = t; i < OUT_F * HID_F; i += 256) {  // W2T[n*64+k] = W2[k*32+n]
    int n = i >> 6, k = i & 63;
    w2t[i] = f2bf(ldf(W2, k * OUT_F + n, f32));
  }
}

// --- CSR build pass 1: per-chunk LDS histogram over buckets ---------------
__global__ __launch_bounds__(256) void k_hist(const void* __restrict__ pe,
                                              int* __restrict__ histmat,
                                              const int* __restrict__ flags,
                                              int E, int N, int CH) {
  __shared__ int hist[NBS];
  int t = threadIdx.x;
  for (int i = t; i < NBS; i += 256) hist[i] = 0;
  __syncthreads();
  int i64 = flags[1];
  int base = blockIdx.x * CH, end = min(base + CH, E);
  for (int e = base + t; e < end; e += 256) {
    int dst = clampN(ldi_nt(pe, (long long)E + e, i64), N);
    atomicAdd(&hist[dst >> 8], 1);       // LDS atomic
  }
  __syncthreads();
  for (int i = t; i < NBS; i += 256) histmat[blockIdx.x * NBS + i] = hist[i];
}

// --- pass 2: per-bucket column exclusive scan over NA=512 chunk rows -------
__global__ __launch_bounds__(256) void k_colscan(int* __restrict__ histmat,
                                                 int* __restrict__ btot) {
  __shared__ int a[NA];                  // 512, two slots per thread
  int b = blockIdx.x, t = threadIdx.x;
  int h0 = histmat[t * NBS + b];
  int h1 = histmat[(t + 256) * NBS + b];
  a[t] = h0; a[t + 256] = h1;
  __syncthreads();
  for (int off = 1; off < NA; off <<= 1) {
    int v0 = (t >= off) ? a[t - off] : 0;
    int v1 = (t + 256 >= off) ? a[t + 256 - off] : 0;
    __syncthreads();
    a[t] += v0; a[t + 256] += v1;
    __syncthreads();
  }
  histmat[t * NBS + b] = a[t] - h0;             // exclusive within column
  histmat[(t + 256) * NBS + b] = a[t + 256] - h1;
  if (t == 255) btot[b] = a[NA - 1];
}

// --- pass 3: scatter pairs into bucket-sorted order (LDS cursors only) -----
__global__ __launch_bounds__(256) void k_scatter(const void* __restrict__ pe,
                                                 const int* __restrict__ histmat,
                                                 const int* __restrict__ btot,
                                                 int2* __restrict__ epairs,
                                                 const int* __restrict__ flags,
                                                 int E, int N, int NB, int CH) {
  __shared__ int sc[NBS];
  __shared__ int cur[NBS];
  int t = threadIdx.x;
  int o0 = (t < NB) ? btot[t] : 0;
  int o1 = (t + 256 < NB) ? btot[t + 256] : 0;
  sc[t] = o0; sc[t + 256] = o1;
  __syncthreads();
  for (int off = 1; off < NBS; off <<= 1) {      // Hillis-Steele, 2 slots/thread
    int v0 = (t >= off) ? sc[t - off] : 0;
    int v1 = (t + 256 >= off) ? sc[t + 256 - off] : 0;
    __syncthreads();
    sc[t] += v0; sc[t + 256] += v1;
    __syncthreads();
  }
  const int* row = histmat + blockIdx.x * NBS;   // contiguous row
  cur[t]       = sc[t] - o0 + row[t];            // bucket base + block cursor
  cur[t + 256] = sc[t + 256] - o1 + row[t + 256];
  __syncthreads();
  int i64 = flags[1];
  int base = blockIdx.x * CH, end = min(base + CH, E);
  for (int e = base + t; e < end; e += 256) {
    int src = clampN(ldi_nt(pe, e, i64), N);
    int dst = clampN(ldi_nt(pe, (long long)E + e, i64), N);
    int pos = atomicAdd(&cur[dst >> 8], 1);      // LDS atomic
    epairs[pos] = make_int2(src, dst);
  }
}

// --- pass 4: per-bucket counting sort -> csr; emits rowp + dinv ------------
__global__ __launch_bounds__(256) void k_bsort(const int2* __restrict__ epairs,
                                               const int* __restrict__ btot,
                                               int* __restrict__ rowp,
                                               float* __restrict__ dinv,
                                               int* __restrict__ csr,
                                               int N, int NB) {
  __shared__ int red[256];
  __shared__ int cnt[256];
  __shared__ int cur2[256];
  __shared__ int s_start;
  int b = blockIdx.x, t = threadIdx.x;
  int acc = 0;
  for (int i = t; i < b; i += 256) acc += btot[i];   // bstart = sum btot[<b]
  red[t] = acc;
  __syncthreads();
  for (int off = 128; off > 0; off >>= 1) {
    if (t < off) red[t] += red[t + off];
    __syncthreads();
  }
  if (t == 0) s_start = red[0];
  __syncthreads();
  int bstart = s_start, bend = bstart + btot[b];
  int node0 = b << 8, nn = min(N - node0, 256);
  cnt[t] = 0;
  __syncthreads();
  for (int j = bstart + t; j < bend; j += 256)
    atomicAdd(&cnt[epairs[j].y - node0], 1);         // LDS atomic
  __syncthreads();
  int c = cnt[t];
  red[t] = c;
  __syncthreads();
  for (int off = 1; off < 256; off <<= 1) {          // inclusive scan
    int v = (t >= off) ? red[t - off] : 0;
    __syncthreads();
    red[t] += v;
    __syncthreads();
  }
  int excl = red[t] - c;
  if (t < nn) {
    rowp[node0 + t] = bstart + excl;
    dinv[node0 + t] = 1.0f / sqrtf((float)(c + 1));  // +1 self loop
    cur2[t] = bstart + excl;
  }
  __syncthreads();
  for (int j = bstart + t; j < bend; j += 256) {
    int2 p = epairs[j];
    int pos = atomicAdd(&cur2[p.y - node0], 1);      // LDS atomic
    csr[pos] = p.x;                                  // ~16KB window: L2-local
  }
  if (b == NB - 1 && t == 0) rowp[N] = bend;
}

// --- gemm1 (MFMA): xw1' = dinv .* (x @ W1), bf16 out -----------------------
__global__ __launch_bounds__(256) void k_gemm1(const void* __restrict__ x,
                                               const unsigned short* __restrict__ w1t,
                                               const float* __restrict__ dinv,
                                               unsigned short* __restrict__ xw1,
                                               const int* __restrict__ flags, int N) {
  int w = threadIdx.x >> 6, lane = threadIdx.x & 63;
  int m = lane & 15, quad = lane >> 4;
  int r0 = blockIdx.x * 64 + w * 16;
  int rr = r0 + m; if (rr >= N) rr = N - 1;
  int f32 = flags[0];
  short8 A[4];
  if (f32) {
    const float* xf = (const float*)x + (size_t)rr * IN_F;
#pragma unroll
    for (int ks = 0; ks < 4; ++ks) {
      const float* p = xf + ks * 32 + quad * 8;
      f32x4 u0 = __builtin_nontemporal_load((const f32x4*)p);
      f32x4 u1 = __builtin_nontemporal_load((const f32x4*)(p + 4));
      short8 a;
#pragma unroll
      for (int j = 0; j < 4; ++j) { a[j] = (short)f2bf(u0[j]); a[4 + j] = (short)f2bf(u1[j]); }
      A[ks] = a;
    }
  } else {
    const unsigned short* xb = (const unsigned short*)x + (size_t)rr * IN_F;
#pragma unroll
    for (int ks = 0; ks < 4; ++ks)
      A[ks] = __builtin_nontemporal_load((const short8*)(xb + ks * 32 + quad * 8));
  }
  float dr[4];
#pragma unroll
  for (int reg = 0; reg < 4; ++reg) {
    int row = r0 + quad * 4 + reg;
    dr[reg] = (row < N) ? dinv[row] : 0.f;
  }
#pragma unroll
  for (int nt = 0; nt < 4; ++nt) {
    f32x4 acc = {0.f, 0.f, 0.f, 0.f};
#pragma unroll
    for (int ks = 0; ks < 4; ++ks) {
      short8 Bf = *(const short8*)(w1t + (nt * 16 + m) * IN_F + ks * 32 + quad * 8);
      acc = __builtin_amdgcn_mfma_f32_16x16x32_bf16(A[ks], Bf, acc, 0, 0, 0);
    }
#pragma unroll
    for (int reg = 0; reg < 4; ++reg) {
      int row = r0 + quad * 4 + reg;
      if (row < N) xw1[(size_t)row * HID_F + nt * 16 + m] = f2bf(dr[reg] * acc[reg]);
    }
  }
}

// --- gather1: h = relu(b1 + dv*(xw1'[v] + sum xw1'[s])), 2-ahead batch -----
__global__ __launch_bounds__(256) void k_gather1(const int* __restrict__ row_ptr,
                                                 const int* __restrict__ csr_src,
                                                 const float* __restrict__ dinv,
                                                 const unsigned short* __restrict__ xw1,
                                                 const void* __restrict__ b1,
                                                 unsigned short* __restrict__ h,
                                                 const int* __restrict__ flags, int N) {
  int v = blockIdx.x * 4 + (threadIdx.x >> 6);
  if (v >= N) return;
  int lane = threadIdx.x & 63;
  int sub = lane >> 3, l8 = lane & 7;
  int start = row_ptr[v], end = row_ptr[v + 1];
  float a[8] = {0.f,0.f,0.f,0.f,0.f,0.f,0.f,0.f};
  int j = start + sub;
  for (; j + 8 < end; j += 16) {         // 2 neighbors per trip, loads batched
    int s0 = __builtin_nontemporal_load(csr_src + j);
    int s1 = __builtin_nontemporal_load(csr_src + j + 8);
    bfx8 w0 = *(const bfx8*)(xw1 + (size_t)s0 * HID_F + l8 * 8);
    bfx8 w1 = *(const bfx8*)(xw1 + (size_t)s1 * HID_F + l8 * 8);
#pragma unroll
    for (int q = 0; q < 8; ++q) a[q] += bf2f(w0[q]);   // order preserved:
#pragma unroll
    for (int q = 0; q < 8; ++q) a[q] += bf2f(w1[q]);   // j then j+8
  }
  if (j < end) {                         // tail: single neighbor
    int s = __builtin_nontemporal_load(csr_src + j);
    bfx8 wv = *(const bfx8*)(xw1 + (size_t)s * HID_F + l8 * 8);
#pragma unroll
    for (int q = 0; q < 8; ++q) a[q] += bf2f(wv[q]);
  }
#pragma unroll
  for (int q = 0; q < 8; ++q) {
    a[q] += __shfl_xor(a[q], 8);
    a[q] += __shfl_xor(a[q], 16);
    a[q] += __shfl_xor(a[q], 32);
  }
  if (sub == 0) {
    float dv = dinv[v];
    bfx8 sw = *(const bfx8*)(xw1 + (size_t)v * HID_F + l8 * 8);  // = dv*xw1[v]
    int f32 = flags[0];
    bfx8 r;
#pragma unroll
    for (int q = 0; q < 8; ++q) {
      float val = ldf(b1, l8 * 8 + q, f32) + dv * (bf2f(sw[q]) + a[q]);
      r[q] = f2bf(fmaxf(val, 0.f));
    }
    *(bfx8*)(h + (size_t)v * HID_F + l8 * 8) = r;
  }
}

// --- gemm2 (MFMA): xw2' = dinv .* (h @ W2), bf16 out -----------------------
__global__ __launch_bounds__(256) void k_gemm2(const unsigned short* __restrict__ h,
                                               const unsigned short* __restrict__ w2t,
                                               const float* __restrict__ dinv,
                                               unsigned short* __restrict__ xw2, int N) {
  int w = threadIdx.x >> 6, lane = threadIdx.x & 63;
  int m = lane & 15, quad = lane >> 4;
  int r0 = blockIdx.x * 64 + w * 16;
  int rr = r0 + m; if (rr >= N) rr = N - 1;
  const unsigned short* hb = h + (size_t)rr * HID_F;
  short8 A[2];
#pragma unroll
  for (int ks = 0; ks < 2; ++ks)
    A[ks] = *(const short8*)(hb + ks * 32 + quad * 8);
  float dr[4];
#pragma unroll
  for (int reg = 0; reg < 4; ++reg) {
    int row = r0 + quad * 4 + reg;
    dr[reg] = (row < N) ? dinv[row] : 0.f;
  }
#pragma unroll
  for (int nt = 0; nt < 2; ++nt) {
    f32x4 acc = {0.f, 0.f, 0.f, 0.f};
#pragma unroll
    for (int ks = 0; ks < 2; ++ks) {
      short8 Bf = *(const short8*)(w2t + (nt * 16 + m) * HID_F + ks * 32 + quad * 8);
      acc = __builtin_amdgcn_mfma_f32_16x16x32_bf16(A[ks], Bf, acc, 0, 0, 0);
    }
#pragma unroll
    for (int reg = 0; reg < 4; ++reg) {
      int row = r0 + quad * 4 + reg;
      if (row < N) xw2[(size_t)row * OUT_F + nt * 16 + m] = f2bf(dr[reg] * acc[reg]);
    }
  }
}

// --- gather2: z = b2 + dv*(xw2'[v] + sum xw2'[s]), 2-ahead batch -----------
__global__ __launch_bounds__(256) void k_gather2(const int* __restrict__ row_ptr,
                                                 const int* __restrict__ csr_src,
                                                 const float* __restrict__ dinv,
                                                 const unsigned short* __restrict__ xw2,
                                                 const void* __restrict__ b2,
                                                 unsigned short* __restrict__ z,
                                                 const int* __restrict__ flags, int N) {
  int v = blockIdx.x * 4 + (threadIdx.x >> 6);
  if (v >= N) return;
  int lane = threadIdx.x & 63;
  int sub = lane >> 3, l8 = lane & 7;
  int start = row_ptr[v], end = row_ptr[v + 1];
  float a[4] = {0.f, 0.f, 0.f, 0.f};
  int j = start + sub;
  for (; j + 8 < end; j += 16) {         // 2 neighbors per trip, loads batched
    int s0 = __builtin_nontemporal_load(csr_src + j);
    int s1 = __builtin_nontemporal_load(csr_src + j + 8);
    bfx4 w0 = *(const bfx4*)(xw2 + (size_t)s0 * OUT_F + l8 * 4);
    bfx4 w1 = *(const bfx4*)(xw2 + (size_t)s1 * OUT_F + l8 * 4);
#pragma unroll
    for (int q = 0; q < 4; ++q) a[q] += bf2f(w0[q]);
#pragma unroll
    for (int q = 0; q < 4; ++q) a[q] += bf2f(w1[q]);
  }
  if (j < end) {                         // tail: single neighbor
    int s = __builtin_nontemporal_load(csr_src + j);
    bfx4 wv = *(const bfx4*)(xw2 + (size_t)s * OUT_F + l8 * 4);
#pragma unroll
    for (int q = 0; q < 4; ++q) a[q] += bf2f(wv[q]);
  }
#pragma unroll
  for (int q = 0; q < 4; ++q) {
    a[q] += __shfl_xor(a[q], 8);
    a[q] += __shfl_xor(a[q], 16);
    a[q] += __shfl_xor(a[q], 32);
  }
  if (sub == 0) {
    float dv = dinv[v];
    bfx4 sw = *(const bfx4*)(xw2 + (size_t)v * OUT_F + l8 * 4);  // = dv*xw2[v]
    int f32 = flags[0];
    bfx4 r;
#pragma unroll
    for (int q = 0; q < 4; ++q)
      r[q] = f2bf(ldf(b2, l8 * 4 + q, f32) + dv * (bf2f(sw[q]) + a[q]));
    *(bfx4*)(z + (size_t)v * OUT_F + l8 * 4) = r;
  }
}

// --- decode: 4 lanes/edge x DEC_U edges/quad; HALF-RANGE per dispatch ------
// e0 = 0 covers pos edges [0,E); e0 = E covers neg edges [E,2E).
__global__ __launch_bounds__(256) void k_decode(const void* __restrict__ pe,
                                                const void* __restrict__ ne,
                                                const unsigned short* __restrict__ z,
                                                float* __restrict__ out,
                                                const int* __restrict__ flags,
                                                int E, int N, int Q, int e0) {
  int q = blockIdx.x * 64 + (threadIdx.x >> 2);  // quad id within half-range
  int g = threadIdx.x & 3;
  int twoE = 2 * E;
  int i64 = flags[1];
  int ee[DEC_U], src[DEC_U], dst[DEC_U];
  bool ok[DEC_U];
#pragma unroll
  for (int u = 0; u < DEC_U; ++u) {              // phase 1: index loads
    int e = e0 + q + u * Q;
    ee[u] = e; ok[u] = (e < twoE);
    src[u] = 0; dst[u] = 0;
    if (ok[u]) {
      if (e < E) { src[u] = ldi_nt(pe, e, i64); dst[u] = ldi_nt(pe, (long long)E + e, i64); }
      else       { src[u] = ldi_nt(ne, e - E, i64); dst[u] = ldi_nt(ne, e, i64); }
    }
  }
  bfx8 av[DEC_U], bv[DEC_U];
#pragma unroll
  for (int u = 0; u < DEC_U; ++u) {              // phase 2: z-row loads
    int cs = clampN(src[u], N), cd = clampN(dst[u], N);
    av[u] = *(const bfx8*)(z + (size_t)cs * OUT_F + g * 8);
    bv[u] = *(const bfx8*)(z + (size_t)cd * OUT_F + g * 8);
  }
#pragma unroll
  for (int u = 0; u < DEC_U; ++u) {              // phase 3: compute + store
    if (!ok[u]) continue;
    int e = ee[u];
    if (g == 1) __builtin_nontemporal_store((float)src[u], out + twoE + e);
    if (g == 2) __builtin_nontemporal_store((float)dst[u], out + 2 * twoE + e);
    float s = 0.f;
#pragma unroll
    for (int k = 0; k < 8; ++k) s += bf2f(av[u][k]) * bf2f(bv[u][k]);
    s += __shfl_xor(s, 1);
    s += __shfl_xor(s, 2);
    s = fminf(fmaxf(s, -500.0f), 500.0f);        // insurance rail (R2 notes)
    if (g == 0) __builtin_nontemporal_store(s, out + e);
  }
}

extern "C" void kernel_launch(void* const* d_in, const int* in_sizes, int n_in,
                              void* d_out, int out_size, void* d_ws, size_t ws_size,
                              hipStream_t stream) {
  const void* x  = d_in[0];
  const void* W1 = d_in[1];
  const void* b1 = d_in[2];
  const void* W2 = d_in[3];
  const void* b2 = d_in[4];
  const void* pe = d_in[5];
  const void* ne = d_in[6];
  int N = in_sizes[0] / IN_F;       // 100000
  int E = in_sizes[5] / 2;          // 1600000
  int NB = (N + 255) >> 8;          // 391 buckets
  int CH = (E + NA - 1) / NA;       // 3125 edges/chunk

  int*   ip    = (int*)d_ws;
  float* ws    = (float*)d_ws;
  int*   flags = ip + OFF_FLAGS;
  unsigned short* w1t = (unsigned short*)(ip + OFF_W1T);
  unsigned short* w2t = (unsigned short*)(ip + OFF_W2T);
  int*   hist  = ip + OFF_H;        // histmat aliases h region (pre-gather1)
  int*   btot  = ip + OFF_BTOT;
  int*   rowp  = ip + OFF_ROWP;
  float* dinv  = ws + OFF_DINV;
  int2*  epairs= (int2*)(ip + OFF_EPAIRS);
  int*   csr   = ip + OFF_CSR;
  unsigned short* xw1 = (unsigned short*)(ip + OFF_XW1);
  unsigned short* h   = (unsigned short*)(ip + OFF_H);
  unsigned short* xw2 = (unsigned short*)(ip + OFF_XW2);
  unsigned short* zz  = (unsigned short*)(ip + OFF_Z);
  float* out   = (float*)d_out;

  k_prep<<<1, 256, 0, stream>>>(x, pe, W1, W2, flags, w1t, w2t);
  k_hist<<<NA, 256, 0, stream>>>(pe, hist, flags, E, N, CH);
  k_colscan<<<NB, 256, 0, stream>>>(hist, btot);
  k_scatter<<<NA, 256, 0, stream>>>(pe, hist, btot, epairs, flags, E, N, NB, CH);
  k_bsort<<<NB, 256, 0, stream>>>(epairs, btot, rowp, dinv, csr, N, NB);
  k_gemm1<<<(N + 63) / 64, 256, 0, stream>>>(x, w1t, dinv, xw1, flags, N);
  k_gather1<<<(N + 3) / 4, 256, 0, stream>>>(rowp, csr, dinv, xw1, b1, h, flags, N);
  k_gemm2<<<(N + 63) / 64, 256, 0, stream>>>(h, w2t, dinv, xw2, N);
  k_gather2<<<(N + 3) / 4, 256, 0, stream>>>(rowp, csr, dinv, xw2, b2, zz, flags, N);
  // decode split into pos/neg half-ranges: visibility probe + uniform branch
  int DB2 = (E + 255) / 256;        // 6250 blocks per half (256 edges/block)
  k_decode<<<DB2, 256, 0, stream>>>(pe, ne, zz, out, flags, E, N, DB2 * 64, 0);
  k_decode<<<DB2, 256, 0, stream>>>(pe, ne, zz, out, flags, E, N, DB2 * 64, E);
}